// Round 2
// baseline (10850.503 us; speedup 1.0000x reference)
//
#include <hip/hip_runtime.h>
#include <math.h>

#define D_ 256
#define KSLOT 32
typedef unsigned short ushort_t;

// ---------- helpers ----------
__device__ __forceinline__ float softplus_f(float x){
  return (x > 20.0f) ? x : log1pf(expf(x));
}
__device__ __forceinline__ unsigned f2ord(float f){
  unsigned b = __float_as_uint(f);
  return (b & 0x80000000u) ? ~b : (b | 0x80000000u);
}
__device__ __forceinline__ float ord2f(unsigned k){
  unsigned b = (k & 0x80000000u) ? (k ^ 0x80000000u) : ~k;
  return __uint_as_float(b);
}
__device__ __forceinline__ float bflo(unsigned u){ return __uint_as_float(u << 16); }
__device__ __forceinline__ float bfhi(unsigned u){ return __uint_as_float(u & 0xFFFF0000u); }
__device__ __forceinline__ ushort_t f2b(float f){   // fp32 -> bf16 RNE
  unsigned u = __float_as_uint(f);
  unsigned r = u + 0x7FFFu + ((u >> 16) & 1u);
  return (ushort_t)(r >> 16);
}
__device__ __forceinline__ float block_reduce_sum(float v, float* sbuf){
  #pragma unroll
  for (int o = 32; o > 0; o >>= 1) v += __shfl_xor(v, o);
  int t = threadIdx.x, wid = t >> 6, lane = t & 63;
  if (lane == 0) sbuf[wid] = v;
  __syncthreads();
  if (t == 0) sbuf[0] = sbuf[0] + sbuf[1] + sbuf[2] + sbuf[3];
  __syncthreads();
  float r = sbuf[0];
  __syncthreads();
  return r;
}

// ---------- zero fill ----------
__global__ __launch_bounds__(256) void zerok(float4* __restrict__ p, size_t n4){
  float4 z; z.x = z.y = z.z = z.w = 0.f;
  for (size_t i = (size_t)blockIdx.x * 256 + threadIdx.x; i < n4; i += (size_t)gridDim.x * 256)
    p[i] = z;
}

// ---------- layernorm forward ----------
__global__ __launch_bounds__(256) void ln_fwd(const float* __restrict__ X, const float* __restrict__ gamma,
    const float* __restrict__ beta, float* __restrict__ G, float* __restrict__ mean, float* __restrict__ rstd)
{
  __shared__ float sbuf[8];
  int n = blockIdx.x, t = threadIdx.x;
  size_t idx = (size_t)n * D_ + t;
  float x = X[idx];
  float mu = block_reduce_sum(x, sbuf) * (1.0f / D_);
  float d = x - mu;
  float var = block_reduce_sum(d * d, sbuf) * (1.0f / D_);
  float rs = rsqrtf(var + 1e-5f);
  G[idx] = d * rs * gamma[t] + beta[t];
  if (t == 0){ mean[n] = mu; rstd[n] = rs; }
}

// ---------- GEMM bodies: 64x64 tile, 256 threads, 4x4 acc ----------
#define GEMM_PROLOGUE \
  __shared__ float As[16][68]; \
  __shared__ float Bs[16][68]; \
  int row0 = blockIdx.y * 64, col0 = blockIdx.x * 64; \
  int t = threadIdx.x; \
  int tx = t & 15, ty = t >> 4; \
  float acc[4][4] = {};

#define GEMM_INNER \
    __syncthreads(); \
    _Pragma("unroll") \
    for (int kk = 0; kk < 16; ++kk){ \
      float4 a = *(const float4*)&As[kk][ty << 2]; \
      float4 b = *(const float4*)&Bs[kk][tx << 2]; \
      float av[4] = {a.x, a.y, a.z, a.w}; \
      float bv[4] = {b.x, b.y, b.z, b.w}; \
      _Pragma("unroll") \
      for (int i = 0; i < 4; ++i) \
        _Pragma("unroll") \
        for (int j = 0; j < 4; ++j) \
          acc[i][j] += av[i] * bv[j]; \
    } \
    __syncthreads();

// C[N,M] = A[N,K] @ B[K,M], bf16 output
__global__ __launch_bounds__(256) void gemm_nn_bf16(const float* __restrict__ A, const float* __restrict__ B,
    ushort_t* __restrict__ C, int K, int M)
{
  GEMM_PROLOGUE
  for (int k0 = 0; k0 < K; k0 += 16){
    { int m = t >> 2, kk = (t & 3) << 2;
      float4 v = *(const float4*)(A + (size_t)(row0 + m) * K + (k0 + kk));
      As[kk+0][m] = v.x; As[kk+1][m] = v.y; As[kk+2][m] = v.z; As[kk+3][m] = v.w; }
    { int kk = t >> 4, nn = (t & 15) << 2;
      float4 v = *(const float4*)(B + (size_t)(k0 + kk) * M + (col0 + nn));
      Bs[kk][nn+0] = v.x; Bs[kk][nn+1] = v.y; Bs[kk][nn+2] = v.z; Bs[kk][nn+3] = v.w; }
    GEMM_INNER
  }
  #pragma unroll
  for (int i = 0; i < 4; ++i){
    ushort_t* dst = C + (size_t)(row0 + (ty << 2) + i) * M + col0 + (tx << 2);
    dst[0] = f2b(acc[i][0]); dst[1] = f2b(acc[i][1]);
    dst[2] = f2b(acc[i][2]); dst[3] = f2b(acc[i][3]);
  }
}

// C[N,M] = A[N,K] @ B[K,M], fp32 output (no accumulate)
__global__ __launch_bounds__(256) void gemm_nn_f32(const float* __restrict__ A, const float* __restrict__ B,
    float* __restrict__ C, int K, int M)
{
  GEMM_PROLOGUE
  for (int k0 = 0; k0 < K; k0 += 16){
    { int m = t >> 2, kk = (t & 3) << 2;
      float4 v = *(const float4*)(A + (size_t)(row0 + m) * K + (k0 + kk));
      As[kk+0][m] = v.x; As[kk+1][m] = v.y; As[kk+2][m] = v.z; As[kk+3][m] = v.w; }
    { int kk = t >> 4, nn = (t & 15) << 2;
      float4 v = *(const float4*)(B + (size_t)(k0 + kk) * M + (col0 + nn));
      Bs[kk][nn+0] = v.x; Bs[kk][nn+1] = v.y; Bs[kk][nn+2] = v.z; Bs[kk][nn+3] = v.w; }
    GEMM_INNER
  }
  #pragma unroll
  for (int i = 0; i < 4; ++i){
    float* dst = C + (size_t)(row0 + (ty << 2) + i) * M + col0 + (tx << 2);
    float4 v; v.x=acc[i][0]; v.y=acc[i][1]; v.z=acc[i][2]; v.w=acc[i][3];
    *(float4*)dst = v;
  }
}

// C[N,M] (+)= A[N,K] @ B^T where B is [M,K] row-major, fp32
__global__ __launch_bounds__(256) void gemm_nt_f32(const float* __restrict__ A, const float* __restrict__ B,
    float* __restrict__ C, int K, int M, int accum)
{
  GEMM_PROLOGUE
  for (int k0 = 0; k0 < K; k0 += 16){
    { int m = t >> 2, kk = (t & 3) << 2;
      float4 v = *(const float4*)(A + (size_t)(row0 + m) * K + (k0 + kk));
      As[kk+0][m] = v.x; As[kk+1][m] = v.y; As[kk+2][m] = v.z; As[kk+3][m] = v.w; }
    { int m = t >> 2, kk = (t & 3) << 2;
      float4 v = *(const float4*)(B + (size_t)(col0 + m) * K + (k0 + kk));
      Bs[kk+0][m] = v.x; Bs[kk+1][m] = v.y; Bs[kk+2][m] = v.z; Bs[kk+3][m] = v.w; }
    GEMM_INNER
  }
  #pragma unroll
  for (int i = 0; i < 4; ++i){
    float* dst = C + (size_t)(row0 + (ty << 2) + i) * M + col0 + (tx << 2);
    if (accum){ dst[0]+=acc[i][0]; dst[1]+=acc[i][1]; dst[2]+=acc[i][2]; dst[3]+=acc[i][3]; }
    else { float4 v; v.x=acc[i][0]; v.y=acc[i][1]; v.z=acc[i][2]; v.w=acc[i][3]; *(float4*)dst = v; }
  }
}

// ---------- Km = B_mem @ W_Km (fp32, tiny) ----------
__global__ __launch_bounds__(256) void km_kernel(const float* __restrict__ Bm, const float* __restrict__ W,
    float* __restrict__ Km)
{
  __shared__ float sb[D_];
  int k = blockIdx.x, t = threadIdx.x;
  sb[t] = Bm[(size_t)k * D_ + t];
  __syncthreads();
  float acc = 0.f;
  for (int d = 0; d < D_; ++d) acc += sb[d] * W[(size_t)d * D_ + t];
  Km[(size_t)k * D_ + t] = acc;
}

// ---------- order-2 edges forward: score + seg max (bf16 inputs) ----------
__global__ __launch_bounds__(256) void edge2_fwd(const ushort_t* __restrict__ Q2, const ushort_t* __restrict__ K2,
    const int* __restrict__ c2, const int* __restrict__ u2, float* __restrict__ s2,
    unsigned* __restrict__ m2enc, int NE_, const float* __restrict__ b2p)
{
  int e = (blockIdx.x << 2) + (threadIdx.x >> 6);
  if (e >= NE_) return;
  int lane = threadIdx.x & 63;
  int c = c2[e], u = u2[e];
  uint2 qw = ((const uint2*)(Q2 + (size_t)c * D_))[lane];
  uint2 kw = ((const uint2*)(K2 + (size_t)u * D_))[lane];
  float v = bflo(qw.x)*bflo(kw.x) + bfhi(qw.x)*bfhi(kw.x)
          + bflo(qw.y)*bflo(kw.y) + bfhi(qw.y)*bfhi(kw.y);
  #pragma unroll
  for (int o = 32; o > 0; o >>= 1) v += __shfl_xor(v, o);
  if (lane == 0){
    float b2 = fminf(softplus_f(*b2p), 5.0f);
    float s = v * b2 * 0.0625f;
    s2[e] = s;
    atomicMax(m2enc + c, f2ord(s));
  }
}

// ---------- w = exp(s - m[seg]); s := w; den[seg] += w ----------
__global__ __launch_bounds__(256) void seg_w(float* __restrict__ s, const unsigned* __restrict__ menc,
    const int* __restrict__ seg, float* __restrict__ den, int n)
{
  int e = blockIdx.x * 256 + threadIdx.x;
  if (e >= n) return;
  int c = seg[e];
  float w = expf(s[e] - ord2f(menc[c]));
  s[e] = w;
  atomicAdd(den + c, w);
}

// ---------- per-segment finalize: accum += sum(lse); den := 1/den ----------
__global__ __launch_bounds__(256) void seg_fin(const unsigned* __restrict__ menc, float* __restrict__ den,
    float* __restrict__ accum, int N_)
{
  __shared__ float sbuf[8];
  int n = blockIdx.x * 256 + threadIdx.x;
  float L = 0.f;
  if (n < N_){
    float dn = den[n];
    if (dn > 0.f){
      L = ord2f(menc[n]) + logf(fmaxf(dn, 1e-30f));
      den[n] = 1.0f / dn;
    } else den[n] = 0.f;
  }
  float bs = block_reduce_sum(L, sbuf);
  if (threadIdx.x == 0) atomicAdd(accum, bs);
}

// ---------- order-2 backward scatter ----------
__global__ __launch_bounds__(256) void edge2_bwd(const ushort_t* __restrict__ Q2, const ushort_t* __restrict__ K2,
    const float* __restrict__ w2, const float* __restrict__ inv2, const int* __restrict__ c2,
    const int* __restrict__ u2, float* __restrict__ dQ2, float* __restrict__ dK2, int NE_,
    const float* __restrict__ l2p)
{
  int e = (blockIdx.x << 2) + (threadIdx.x >> 6);
  if (e >= NE_) return;
  int lane = threadIdx.x & 63;
  int c = c2[e], u = u2[e];
  float coef = -softplus_f(*l2p) * 0.0625f * w2[e] * inv2[c];
  uint2 qw = ((const uint2*)(Q2 + (size_t)c * D_))[lane];
  uint2 kw = ((const uint2*)(K2 + (size_t)u * D_))[lane];
  float* dq = dQ2 + (size_t)c * D_ + (lane << 2);
  float* dk = dK2 + (size_t)u * D_ + (lane << 2);
  atomicAdd(dq + 0, coef * bflo(kw.x)); atomicAdd(dq + 1, coef * bfhi(kw.x));
  atomicAdd(dq + 2, coef * bflo(kw.y)); atomicAdd(dq + 3, coef * bfhi(kw.y));
  atomicAdd(dk + 0, coef * bflo(qw.x)); atomicAdd(dk + 1, coef * bfhi(qw.x));
  atomicAdd(dk + 2, coef * bflo(qw.y)); atomicAdd(dk + 3, coef * bfhi(qw.y));
}

// ---------- order-3 triangles forward ----------
__global__ __launch_bounds__(256) void tri_fwd(const ushort_t* __restrict__ Q3, const ushort_t* __restrict__ K3,
    const float* __restrict__ Tt, const int* __restrict__ c3, const int* __restrict__ u3,
    const int* __restrict__ v3, const int* __restrict__ tt, float* __restrict__ s3,
    unsigned* __restrict__ m3enc, int NT_, const float* __restrict__ b3p)
{
  int tr = (blockIdx.x << 2) + (threadIdx.x >> 6);
  if (tr >= NT_) return;
  int lane = threadIdx.x & 63;
  int c = c3[tr], u = u3[tr], v = v3[tr], tau = tt[tr];
  uint4 qa = ((const uint4*)(Q3 + (size_t)c * 2 * D_))[lane];
  uint4 kb = ((const uint4*)(K3 + (size_t)u * 2 * D_))[lane];
  uint4 kc = ((const uint4*)(K3 + (size_t)v * 2 * D_))[lane];
  const float4* tp = (const float4*)(Tt + (size_t)tau * 2 * D_);
  float4 t0 = tp[2 * lane], t1 = tp[2 * lane + 1];
  float acc = bflo(qa.x)*bflo(kb.x)*bflo(kc.x)*t0.x + bfhi(qa.x)*bfhi(kb.x)*bfhi(kc.x)*t0.y
            + bflo(qa.y)*bflo(kb.y)*bflo(kc.y)*t0.z + bfhi(qa.y)*bfhi(kb.y)*bfhi(kc.y)*t0.w
            + bflo(qa.z)*bflo(kb.z)*bflo(kc.z)*t1.x + bfhi(qa.z)*bfhi(kb.z)*bfhi(kc.z)*t1.y
            + bflo(qa.w)*bflo(kb.w)*bflo(kc.w)*t1.z + bfhi(qa.w)*bfhi(kb.w)*bfhi(kc.w)*t1.w;
  #pragma unroll
  for (int o = 32; o > 0; o >>= 1) acc += __shfl_xor(acc, o);
  if (lane == 0){
    float b3 = fminf(softplus_f(*b3p), 5.0f);
    float s = acc * b3 * 0.0625f;
    s3[tr] = s;
    atomicMax(m3enc + c, f2ord(s));
  }
}

// ---------- order-3 backward scatter (mode 0: dQ3; mode 1: dK3 u and v) ----------
__global__ __launch_bounds__(256) void tri_bwd(const ushort_t* __restrict__ Q3, const ushort_t* __restrict__ K3,
    const float* __restrict__ Tt, const int* __restrict__ c3, const int* __restrict__ u3,
    const int* __restrict__ v3, const int* __restrict__ tt, const float* __restrict__ w3,
    const float* __restrict__ inv3, float* __restrict__ dOut, int NT_,
    const float* __restrict__ l3p, int mode)
{
  int tr = (blockIdx.x << 2) + (threadIdx.x >> 6);
  if (tr >= NT_) return;
  int lane = threadIdx.x & 63;
  int c = c3[tr], u = u3[tr], v = v3[tr], tau = tt[tr];
  float C = -softplus_f(*l3p) * 0.0625f * w3[tr] * inv3[c];
  uint4 qa = ((const uint4*)(Q3 + (size_t)c * 2 * D_))[lane];
  uint4 kb = ((const uint4*)(K3 + (size_t)u * 2 * D_))[lane];
  uint4 kc = ((const uint4*)(K3 + (size_t)v * 2 * D_))[lane];
  const float4* tp = (const float4*)(Tt + (size_t)tau * 2 * D_);
  float4 t0 = tp[2 * lane], t1 = tp[2 * lane + 1];
  float q[8] = {bflo(qa.x),bfhi(qa.x),bflo(qa.y),bfhi(qa.y),bflo(qa.z),bfhi(qa.z),bflo(qa.w),bfhi(qa.w)};
  float b[8] = {bflo(kb.x),bfhi(kb.x),bflo(kb.y),bfhi(kb.y),bflo(kb.z),bfhi(kb.z),bflo(kb.w),bfhi(kb.w)};
  float cc[8]= {bflo(kc.x),bfhi(kc.x),bflo(kc.y),bfhi(kc.y),bflo(kc.z),bfhi(kc.z),bflo(kc.w),bfhi(kc.w)};
  float td[8]= {t0.x,t0.y,t0.z,t0.w,t1.x,t1.y,t1.z,t1.w};
  int base = lane << 3;
  if (mode == 0){
    float* dq = dOut + (size_t)c * 2 * D_ + base;
    #pragma unroll
    for (int i = 0; i < 8; ++i) atomicAdd(dq + i, C * b[i] * cc[i] * td[i]);
  } else {
    float* dku = dOut + (size_t)u * 2 * D_ + base;
    float* dkv = dOut + (size_t)v * 2 * D_ + base;
    #pragma unroll
    for (int i = 0; i < 8; ++i) atomicAdd(dku + i, C * q[i] * cc[i] * td[i]);
    #pragma unroll
    for (int i = 0; i < 8; ++i) atomicAdd(dkv + i, C * q[i] * b[i] * td[i]);
  }
}

// ---------- memory term: per-row softmax over 32 slots, lse, dQm in place ----------
__global__ __launch_bounds__(256) void mem_rows(float* __restrict__ Qm, const float* __restrict__ Km,
    float* __restrict__ lseM, const float* __restrict__ bmp, const float* __restrict__ lmp)
{
  __shared__ float sKm[KSLOT * D_];
  __shared__ float sq[D_];
  __shared__ float sS[KSLOT];
  int n = blockIdx.x, t = threadIdx.x;
  for (int i = t; i < KSLOT * D_ / 4; i += 256)
    ((float4*)sKm)[i] = ((const float4*)Km)[i];
  sq[t] = Qm[(size_t)n * D_ + t];
  __syncthreads();
  float bm = fminf(softplus_f(*bmp), 5.0f);
  int g = t >> 3, i = t & 7;
  float part = 0.f;
  int d0 = i * 32;
  #pragma unroll 8
  for (int d = d0; d < d0 + 32; ++d) part += sq[d] * sKm[g * D_ + d];
  part += __shfl_xor(part, 1); part += __shfl_xor(part, 2); part += __shfl_xor(part, 4);
  if (i == 0) sS[g] = part * bm * 0.0625f;
  __syncthreads();
  if (t < 32){
    float v = sS[t];
    float m = v;
    #pragma unroll
    for (int o = 16; o > 0; o >>= 1) m = fmaxf(m, __shfl_xor(m, o));
    float e = expf(v - m);
    float se = e;
    #pragma unroll
    for (int o = 16; o > 0; o >>= 1) se += __shfl_xor(se, o);
    sS[t] = e / se;
    if (t == 0) lseM[n] = m + logf(se);
  }
  __syncthreads();
  float acc = 0.f;
  #pragma unroll 8
  for (int k = 0; k < KSLOT; ++k) acc += sS[k] * sKm[k * D_ + t];
  float lam = softplus_f(*lmp);
  Qm[(size_t)n * D_ + t] = -lam * 0.0625f * acc;
}

// ---------- sum reduce ----------
__global__ __launch_bounds__(256) void reduce_sum(const float* __restrict__ v, int n, float* __restrict__ accum)
{
  __shared__ float sbuf[8];
  float acc = 0.f;
  for (int i = blockIdx.x * 256 + threadIdx.x; i < n; i += gridDim.x * 256) acc += v[i];
  float bs = block_reduce_sum(acc, sbuf);
  if (threadIdx.x == 0) atomicAdd(accum, bs);
}

// ---------- LN backward + grad clip + step + state clip ----------
__global__ __launch_bounds__(256) void ln_bwd_update(const float* __restrict__ X, const float* __restrict__ dG,
    const float* __restrict__ gamma, const float* __restrict__ mean, const float* __restrict__ rstd,
    const float* __restrict__ step_p, float* __restrict__ out)
{
  __shared__ float sbuf[8];
  int n = blockIdx.x, t = threadIdx.x;
  size_t idx = (size_t)n * D_ + t;
  float x = X[idx];
  float rs = rstd[n];
  float xh = (x - mean[n]) * rs;
  float dxh = dG[idx] * gamma[t];
  float s1 = block_reduce_sum(dxh, sbuf) * (1.0f / D_);
  float s2v = block_reduce_sum(dxh * xh, sbuf) * (1.0f / D_);
  float dx = rs * (dxh - s1 - xh * s2v);
  float gn2 = block_reduce_sum(dx * dx, sbuf);
  float gn = fmaxf(sqrtf(gn2), 1e-6f);
  float gsc = fminf(1.0f / gn, 1.0f);
  float stp = step_p[0] * 0.9999f;
  float xn = x - stp * gsc * dx;
  float sn2 = block_reduce_sum(xn * xn, sbuf);
  float sn = fmaxf(sqrtf(sn2), 1e-6f);
  float ssc = fminf(10.0f / sn, 1.0f);
  out[idx] = xn * ssc;
}

// ---------- final energy scalar ----------
__global__ void efinal(const float* __restrict__ accum, const float* l2p, const float* l3p, const float* lmp,
    const float* b2p, const float* b3p, const float* bmp, float* __restrict__ outE)
{
  float l2 = softplus_f(*l2p), l3 = softplus_f(*l3p), lm = softplus_f(*lmp);
  float b2 = fminf(softplus_f(*b2p), 5.0f);
  float b3 = fminf(softplus_f(*b3p), 5.0f);
  float bm = fminf(softplus_f(*bmp), 5.0f);
  *outE = -(l2 / b2) * accum[0] - (l3 / b3) * accum[1] - (lm / bm) * accum[2];
}

static inline void zfill(float* p, size_t nElems, hipStream_t stream){
  size_t n4 = nElems / 4;
  int blocks = (int)(((n4 + 255) / 256) < 16384 ? ((n4 + 255) / 256) : 16384);
  if (blocks < 1) blocks = 1;
  zerok<<<blocks, 256, 0, stream>>>((float4*)p, n4);
}

extern "C" void kernel_launch(void* const* d_in, const int* in_sizes, int n_in,
                              void* d_out, int out_size, void* d_ws, size_t ws_size,
                              hipStream_t stream)
{
  const float* X     = (const float*)d_in[0];
  const int*   c2    = (const int*)d_in[1];
  const int*   u2    = (const int*)d_in[2];
  const int*   c3    = (const int*)d_in[3];
  const int*   u3    = (const int*)d_in[4];
  const int*   v3    = (const int*)d_in[5];
  const int*   tt    = (const int*)d_in[6];
  const float* stepp = (const float*)d_in[7];
  const float* gamma = (const float*)d_in[8];
  const float* beta  = (const float*)d_in[9];
  const float* W_Q2  = (const float*)d_in[10];
  const float* W_K2  = (const float*)d_in[11];
  const float* W_Q3  = (const float*)d_in[12];
  const float* W_K3  = (const float*)d_in[13];
  const float* T_tau = (const float*)d_in[14];
  const float* W_Qm  = (const float*)d_in[15];
  const float* W_Km  = (const float*)d_in[16];
  const float* B_mem = (const float*)d_in[17];
  const float* l2p   = (const float*)d_in[18];
  const float* l3p   = (const float*)d_in[19];
  const float* lmp   = (const float*)d_in[20];
  const float* b2p   = (const float*)d_in[21];
  const float* b3p   = (const float*)d_in[22];
  const float* bmp   = (const float*)d_in[23];

  const int N  = in_sizes[0] / D_;
  const int NE = in_sizes[1];
  const int NT = in_sizes[3];
  const size_t ND = (size_t)N * D_;

  // ---- byte arena (peak ~172 MB) ----
  char* base = (char*)d_ws;
  size_t off = 0;
  auto alloc = [&](size_t bytes) -> void* {
    void* p = base + off;
    off += (bytes + 255) & ~(size_t)255;
    return p;
  };
  float*    G    = (float*)   alloc(ND * 4);
  ushort_t* Q3b  = (ushort_t*)alloc(ND * 2 * 2);   // doubles as Q2b (order-2 phase)
  ushort_t* K3b  = (ushort_t*)alloc(ND * 2 * 2);   // doubles as K2b
  float*    dbuf = (float*)   alloc(ND * 2 * 4);   // Qm/dQm -> dQ2|dK2 -> dQ3 -> dK3
  float*    s2   = (float*)   alloc((size_t)NE * 4);
  float*    s3   = (float*)   alloc((size_t)NT * 4);
  float*    Km   = (float*)   alloc((size_t)KSLOT * D_ * 4);
  float*    meanb= (float*)   alloc((size_t)N * 4);
  float*    rstdb= (float*)   alloc((size_t)N * 4);
  unsigned* m2enc= (unsigned*)alloc((size_t)N * 4);
  float*    den2 = (float*)   alloc((size_t)N * 4);
  unsigned* m3enc= (unsigned*)alloc((size_t)N * 4);
  float*    den3 = (float*)   alloc((size_t)N * 4);
  float*    lseM = (float*)   alloc((size_t)N * 4);
  float*    accum= (float*)   alloc(64);

  float* out = (float*)d_out;     // out[0:ND] doubles as dG until the final kernel
  ushort_t* Q2b = Q3b;
  ushort_t* K2b = K3b;

  // zero the stats buffers
  zfill((float*)m2enc, N, stream);
  zfill(den2, N, stream);
  zfill((float*)m3enc, N, stream);
  zfill(den3, N, stream);
  zfill(accum, 16, stream);

  // 1. LN forward
  ln_fwd<<<N, 256, 0, stream>>>(X, gamma, beta, G, meanb, rstdb);

  dim3 g256(D_ / 64, N / 64);         // M=256 outputs
  dim3 g512(2 * D_ / 64, N / 64);     // M=512 outputs

  // 2. memory term first (dbuf = Qm then dQm)
  gemm_nn_f32<<<g256, 256, 0, stream>>>(G, W_Qm, dbuf, D_, D_);
  km_kernel<<<KSLOT, 256, 0, stream>>>(B_mem, W_Km, Km);
  mem_rows<<<N, 256, 0, stream>>>(dbuf, Km, lseM, bmp, lmp);
  reduce_sum<<<128, 256, 0, stream>>>(lseM, N, accum + 2);
  gemm_nt_f32<<<g256, 256, 0, stream>>>(dbuf, W_Qm, out, D_, D_, 0);  // dG = dQm W_Qm^T

  // 3. order-2 term
  gemm_nn_bf16<<<g256, 256, 0, stream>>>(G, W_Q2, Q2b, D_, D_);
  gemm_nn_bf16<<<g256, 256, 0, stream>>>(G, W_K2, K2b, D_, D_);
  zfill(dbuf, ND * 2, stream);                                         // dQ2 | dK2
  edge2_fwd<<<(NE + 3) / 4, 256, 0, stream>>>(Q2b, K2b, c2, u2, s2, m2enc, NE, b2p);
  seg_w<<<(NE + 255) / 256, 256, 0, stream>>>(s2, m2enc, c2, den2, NE);
  seg_fin<<<(N + 255) / 256, 256, 0, stream>>>(m2enc, den2, accum + 0, N);
  edge2_bwd<<<(NE + 3) / 4, 256, 0, stream>>>(Q2b, K2b, s2, den2, c2, u2, dbuf, dbuf + ND, NE, l2p);
  gemm_nt_f32<<<g256, 256, 0, stream>>>(dbuf,      W_Q2, out, D_, D_, 1);
  gemm_nt_f32<<<g256, 256, 0, stream>>>(dbuf + ND, W_K2, out, D_, D_, 1);

  // 4. order-3 term (Q3b/K3b overwrite Q2b/K2b — order-2 fully retired)
  gemm_nn_bf16<<<g512, 256, 0, stream>>>(G, W_Q3, Q3b, D_, 2 * D_);
  gemm_nn_bf16<<<g512, 256, 0, stream>>>(G, W_K3, K3b, D_, 2 * D_);
  tri_fwd<<<(NT + 3) / 4, 256, 0, stream>>>(Q3b, K3b, T_tau, c3, u3, v3, tt, s3, m3enc, NT, b3p);
  seg_w<<<(NT + 255) / 256, 256, 0, stream>>>(s3, m3enc, c3, den3, NT);
  seg_fin<<<(N + 255) / 256, 256, 0, stream>>>(m3enc, den3, accum + 1, N);
  // pass 1: dQ3
  zfill(dbuf, ND * 2, stream);
  tri_bwd<<<(NT + 3) / 4, 256, 0, stream>>>(Q3b, K3b, T_tau, c3, u3, v3, tt, s3, den3, dbuf, NT, l3p, 0);
  gemm_nt_f32<<<g256, 256, 0, stream>>>(dbuf, W_Q3, out, 2 * D_, D_, 1);
  // pass 2: dK3
  zfill(dbuf, ND * 2, stream);
  tri_bwd<<<(NT + 3) / 4, 256, 0, stream>>>(Q3b, K3b, T_tau, c3, u3, v3, tt, s3, den3, dbuf, NT, l3p, 1);
  gemm_nt_f32<<<g256, 256, 0, stream>>>(dbuf, W_K3, out, 2 * D_, D_, 1);

  // 5. LN backward + clips + update (in place over out)
  ln_bwd_update<<<N, 256, 0, stream>>>(X, out, gamma, meanb, rstdb, stepp, out);

  // 6. energy scalar
  efinal<<<1, 1, 0, stream>>>(accum, l2p, l3p, lmp, b2p, b3p, bmp, out + ND);
}

// Round 3
// 2391.180 us; speedup vs baseline: 4.5377x; 4.5377x over previous
//
#include <hip/hip_runtime.h>
#include <math.h>

#define D_ 256
#define KSLOT 32
typedef unsigned short ushort_t;

// ---------- helpers ----------
__device__ __forceinline__ float softplus_f(float x){
  return (x > 20.0f) ? x : log1pf(expf(x));
}
__device__ __forceinline__ float bflo(unsigned u){ return __uint_as_float(u << 16); }
__device__ __forceinline__ float bfhi(unsigned u){ return __uint_as_float(u & 0xFFFF0000u); }
__device__ __forceinline__ ushort_t f2b(float f){   // fp32 -> bf16 RNE
  unsigned u = __float_as_uint(f);
  unsigned r = u + 0x7FFFu + ((u >> 16) & 1u);
  return (ushort_t)(r >> 16);
}
__device__ __forceinline__ float block_reduce_sum(float v, float* sbuf){
  #pragma unroll
  for (int o = 32; o > 0; o >>= 1) v += __shfl_xor(v, o);
  int t = threadIdx.x, wid = t >> 6, lane = t & 63;
  if (lane == 0) sbuf[wid] = v;
  __syncthreads();
  if (t == 0) sbuf[0] = sbuf[0] + sbuf[1] + sbuf[2] + sbuf[3];
  __syncthreads();
  float r = sbuf[0];
  __syncthreads();
  return r;
}

// ---------- zero fill ----------
__global__ __launch_bounds__(256) void zerok(float4* __restrict__ p, size_t n4){
  float4 z; z.x = z.y = z.z = z.w = 0.f;
  for (size_t i = (size_t)blockIdx.x * 256 + threadIdx.x; i < n4; i += (size_t)gridDim.x * 256)
    p[i] = z;
}

// ---------- layernorm forward ----------
__global__ __launch_bounds__(256) void ln_fwd(const float* __restrict__ X, const float* __restrict__ gamma,
    const float* __restrict__ beta, float* __restrict__ G, float* __restrict__ mean, float* __restrict__ rstd)
{
  __shared__ float sbuf[8];
  int n = blockIdx.x, t = threadIdx.x;
  size_t idx = (size_t)n * D_ + t;
  float x = X[idx];
  float mu = block_reduce_sum(x, sbuf) * (1.0f / D_);
  float d = x - mu;
  float var = block_reduce_sum(d * d, sbuf) * (1.0f / D_);
  float rs = rsqrtf(var + 1e-5f);
  G[idx] = d * rs * gamma[t] + beta[t];
  if (t == 0){ mean[n] = mu; rstd[n] = rs; }
}

// ---------- GEMM 64x64 tile, 256 threads, 4x4 acc ----------
#define GEMM_PROLOGUE \
  __shared__ float As[16][68]; \
  __shared__ float Bs[16][68]; \
  int row0 = blockIdx.y * 64, col0 = blockIdx.x * 64; \
  int t = threadIdx.x; \
  int tx = t & 15, ty = t >> 4; \
  float acc[4][4] = {};

#define GEMM_INNER \
    __syncthreads(); \
    _Pragma("unroll") \
    for (int kk = 0; kk < 16; ++kk){ \
      float4 a = *(const float4*)&As[kk][ty << 2]; \
      float4 b = *(const float4*)&Bs[kk][tx << 2]; \
      float av[4] = {a.x, a.y, a.z, a.w}; \
      float bv[4] = {b.x, b.y, b.z, b.w}; \
      _Pragma("unroll") \
      for (int i = 0; i < 4; ++i) \
        _Pragma("unroll") \
        for (int j = 0; j < 4; ++j) \
          acc[i][j] += av[i] * bv[j]; \
    } \
    __syncthreads();

__global__ __launch_bounds__(256) void gemm_nn_bf16(const float* __restrict__ A, const float* __restrict__ B,
    ushort_t* __restrict__ C, int K, int M)
{
  GEMM_PROLOGUE
  for (int k0 = 0; k0 < K; k0 += 16){
    { int m = t >> 2, kk = (t & 3) << 2;
      float4 v = *(const float4*)(A + (size_t)(row0 + m) * K + (k0 + kk));
      As[kk+0][m] = v.x; As[kk+1][m] = v.y; As[kk+2][m] = v.z; As[kk+3][m] = v.w; }
    { int kk = t >> 4, nn = (t & 15) << 2;
      float4 v = *(const float4*)(B + (size_t)(k0 + kk) * M + (col0 + nn));
      Bs[kk][nn+0] = v.x; Bs[kk][nn+1] = v.y; Bs[kk][nn+2] = v.z; Bs[kk][nn+3] = v.w; }
    GEMM_INNER
  }
  #pragma unroll
  for (int i = 0; i < 4; ++i){
    ushort_t* dst = C + (size_t)(row0 + (ty << 2) + i) * M + col0 + (tx << 2);
    dst[0] = f2b(acc[i][0]); dst[1] = f2b(acc[i][1]);
    dst[2] = f2b(acc[i][2]); dst[3] = f2b(acc[i][3]);
  }
}

__global__ __launch_bounds__(256) void gemm_nn_f32(const float* __restrict__ A, const float* __restrict__ B,
    float* __restrict__ C, int K, int M)
{
  GEMM_PROLOGUE
  for (int k0 = 0; k0 < K; k0 += 16){
    { int m = t >> 2, kk = (t & 3) << 2;
      float4 v = *(const float4*)(A + (size_t)(row0 + m) * K + (k0 + kk));
      As[kk+0][m] = v.x; As[kk+1][m] = v.y; As[kk+2][m] = v.z; As[kk+3][m] = v.w; }
    { int kk = t >> 4, nn = (t & 15) << 2;
      float4 v = *(const float4*)(B + (size_t)(k0 + kk) * M + (col0 + nn));
      Bs[kk][nn+0] = v.x; Bs[kk][nn+1] = v.y; Bs[kk][nn+2] = v.z; Bs[kk][nn+3] = v.w; }
    GEMM_INNER
  }
  #pragma unroll
  for (int i = 0; i < 4; ++i){
    float* dst = C + (size_t)(row0 + (ty << 2) + i) * M + col0 + (tx << 2);
    float4 v; v.x=acc[i][0]; v.y=acc[i][1]; v.z=acc[i][2]; v.w=acc[i][3];
    *(float4*)dst = v;
  }
}

__global__ __launch_bounds__(256) void gemm_nt_f32(const float* __restrict__ A, const float* __restrict__ B,
    float* __restrict__ C, int K, int M, int accum)
{
  GEMM_PROLOGUE
  for (int k0 = 0; k0 < K; k0 += 16){
    { int m = t >> 2, kk = (t & 3) << 2;
      float4 v = *(const float4*)(A + (size_t)(row0 + m) * K + (k0 + kk));
      As[kk+0][m] = v.x; As[kk+1][m] = v.y; As[kk+2][m] = v.z; As[kk+3][m] = v.w; }
    { int m = t >> 2, kk = (t & 3) << 2;
      float4 v = *(const float4*)(B + (size_t)(col0 + m) * K + (k0 + kk));
      Bs[kk+0][m] = v.x; Bs[kk+1][m] = v.y; Bs[kk+2][m] = v.z; Bs[kk+3][m] = v.w; }
    GEMM_INNER
  }
  #pragma unroll
  for (int i = 0; i < 4; ++i){
    float* dst = C + (size_t)(row0 + (ty << 2) + i) * M + col0 + (tx << 2);
    if (accum){ dst[0]+=acc[i][0]; dst[1]+=acc[i][1]; dst[2]+=acc[i][2]; dst[3]+=acc[i][3]; }
    else { float4 v; v.x=acc[i][0]; v.y=acc[i][1]; v.z=acc[i][2]; v.w=acc[i][3]; *(float4*)dst = v; }
  }
}

// ---------- Km = B_mem @ W_Km ----------
__global__ __launch_bounds__(256) void km_kernel(const float* __restrict__ Bm, const float* __restrict__ W,
    float* __restrict__ Km)
{
  __shared__ float sb[D_];
  int k = blockIdx.x, t = threadIdx.x;
  sb[t] = Bm[(size_t)k * D_ + t];
  __syncthreads();
  float acc = 0.f;
  for (int d = 0; d < D_; ++d) acc += sb[d] * W[(size_t)d * D_ + t];
  Km[(size_t)k * D_ + t] = acc;
}

// ---------- CSR build: histogram ----------
__global__ __launch_bounds__(256) void hist2(const int* __restrict__ c2, const int* __restrict__ u2,
    int* __restrict__ cnt_c, int* __restrict__ cnt_u, int NE_)
{
  int e = blockIdx.x * 256 + threadIdx.x;
  if (e >= NE_) return;
  atomicAdd(cnt_c + c2[e], 1);
  atomicAdd(cnt_u + u2[e], 1);
}
__global__ __launch_bounds__(256) void hist3(const int* __restrict__ c3, const int* __restrict__ u3,
    const int* __restrict__ v3, int* __restrict__ cnt_c, int* __restrict__ cnt_i, int NT_)
{
  int e = blockIdx.x * 256 + threadIdx.x;
  if (e >= NT_) return;
  atomicAdd(cnt_c + c3[e], 1);
  atomicAdd(cnt_i + u3[e], 1);
  atomicAdd(cnt_i + v3[e], 1);
}

// ---------- exclusive scan in place (single block, n multiple of 256) ----------
__global__ __launch_bounds__(256) void scan_excl(int* __restrict__ d, int n)
{
  __shared__ int wsum[4];
  __shared__ int carry;
  int t = threadIdx.x, lane = t & 63, wid = t >> 6;
  if (t == 0) carry = 0;
  __syncthreads();
  for (int base = 0; base < n; base += 256){
    int v = d[base + t];
    int x = v;
    #pragma unroll
    for (int o = 1; o < 64; o <<= 1){
      int y = __shfl_up(x, o);
      if (lane >= o) x += y;
    }
    if (lane == 63) wsum[wid] = x;
    __syncthreads();
    int woff = 0;
    for (int i = 0; i < wid; ++i) woff += wsum[i];
    int excl = carry + woff + x - v;
    d[base + t] = excl;
    __syncthreads();
    if (t == 255) carry = carry + woff + x;
    __syncthreads();
  }
}

// ---------- scatter into CSR (cursor = exclusive offsets; ends up = row ends) ----------
__global__ __launch_bounds__(256) void scatter2(const int* __restrict__ c2, const int* __restrict__ u2,
    int* __restrict__ cur_c, int* __restrict__ cur_u, int* __restrict__ adjc_u, int* __restrict__ adju_c, int NE_)
{
  int e = blockIdx.x * 256 + threadIdx.x;
  if (e >= NE_) return;
  int c = c2[e], u = u2[e];
  int pc = atomicAdd(cur_c + c, 1);
  adjc_u[pc] = u;
  int pu = atomicAdd(cur_u + u, 1);
  adju_c[pu] = c;
}
__global__ __launch_bounds__(256) void scatter3(const int* __restrict__ c3, const int* __restrict__ u3,
    const int* __restrict__ v3, const int* __restrict__ tt, int* __restrict__ cur_c, int* __restrict__ cur_i,
    unsigned* __restrict__ adj3c, unsigned* __restrict__ adj3i, int NT_)
{
  int e = blockIdx.x * 256 + threadIdx.x;
  if (e >= NT_) return;
  int c = c3[e], u = u3[e], v = v3[e], tau = tt[e];
  int pc = atomicAdd(cur_c + c, 1);
  adj3c[pc] = (unsigned)u | ((unsigned)v << 15) | ((unsigned)tau << 30);
  int pu = atomicAdd(cur_i + u, 1);
  adj3i[pu] = (unsigned)c | ((unsigned)v << 15) | ((unsigned)tau << 30);
  int pv = atomicAdd(cur_i + v, 1);
  adj3i[pv] = (unsigned)c | ((unsigned)u << 15) | ((unsigned)tau << 30);
}

// ---------- order-2 by-c: online softmax + dQ2, wave per row ----------
__global__ __launch_bounds__(256) void e2_rowc(const ushort_t* __restrict__ Q2, const ushort_t* __restrict__ K2,
    const int* __restrict__ cur_c, const int* __restrict__ adjc_u, float* __restrict__ dQ2,
    float* __restrict__ m_row, float* __restrict__ linv_row, float* __restrict__ accum, int N_,
    const float* __restrict__ b2p, const float* __restrict__ l2p)
{
  __shared__ float sbuf[4];
  int r = blockIdx.x * 4 + (threadIdx.x >> 6);
  int lane = threadIdx.x & 63;
  float b2s = fminf(softplus_f(*b2p), 5.0f) * 0.0625f;
  float lam2 = softplus_f(*l2p);
  int start = (r > 0) ? cur_c[r - 1] : 0;
  int end = cur_c[r];
  uint2 qw = ((const uint2*)(Q2 + (size_t)r * D_))[lane];
  float q0 = bflo(qw.x), q1 = bfhi(qw.x), q2 = bflo(qw.y), q3 = bfhi(qw.y);
  float m = -1e30f, l = 0.f;
  float a0 = 0.f, a1 = 0.f, a2 = 0.f, a3 = 0.f;
  for (int p = start; p < end; ++p){
    int u = adjc_u[p];
    uint2 kw = ((const uint2*)(K2 + (size_t)u * D_))[lane];
    float k0 = bflo(kw.x), k1 = bfhi(kw.x), k2 = bflo(kw.y), k3 = bfhi(kw.y);
    float d = q0*k0 + q1*k1 + q2*k2 + q3*k3;
    #pragma unroll
    for (int o = 32; o > 0; o >>= 1) d += __shfl_xor(d, o);
    float s = d * b2s;
    float mn = fmaxf(m, s);
    float sc = expf(m - mn);
    float pt = expf(s - mn);
    l = l * sc + pt;
    a0 = a0*sc + pt*k0; a1 = a1*sc + pt*k1; a2 = a2*sc + pt*k2; a3 = a3*sc + pt*k3;
    m = mn;
  }
  float lse = 0.f, linv = 0.f, coef = 0.f;
  if (end > start){ lse = m + logf(l); linv = 1.0f / l; coef = -lam2 * 0.0625f * linv; }
  float4 o4; o4.x = coef*a0; o4.y = coef*a1; o4.z = coef*a2; o4.w = coef*a3;
  *(float4*)(dQ2 + (size_t)r * D_ + (lane << 2)) = o4;
  if (lane == 0){ m_row[r] = m; linv_row[r] = linv; sbuf[threadIdx.x >> 6] = lse; }
  __syncthreads();
  if (threadIdx.x == 0) atomicAdd(accum, sbuf[0] + sbuf[1] + sbuf[2] + sbuf[3]);
}

// ---------- order-2 by-u: dK2, wave per row ----------
__global__ __launch_bounds__(256) void e2_rowu(const ushort_t* __restrict__ Q2, const ushort_t* __restrict__ K2,
    const int* __restrict__ cur_u, const int* __restrict__ adju_c, float* __restrict__ dK2,
    const float* __restrict__ m_row, const float* __restrict__ linv_row, int N_,
    const float* __restrict__ b2p, const float* __restrict__ l2p)
{
  int r = blockIdx.x * 4 + (threadIdx.x >> 6);
  int lane = threadIdx.x & 63;
  float b2s = fminf(softplus_f(*b2p), 5.0f) * 0.0625f;
  float lam2 = softplus_f(*l2p);
  int start = (r > 0) ? cur_u[r - 1] : 0;
  int end = cur_u[r];
  uint2 kw = ((const uint2*)(K2 + (size_t)r * D_))[lane];
  float k0 = bflo(kw.x), k1 = bfhi(kw.x), k2 = bflo(kw.y), k3 = bfhi(kw.y);
  float a0 = 0.f, a1 = 0.f, a2 = 0.f, a3 = 0.f;
  for (int p = start; p < end; ++p){
    int c = adju_c[p];
    uint2 qw = ((const uint2*)(Q2 + (size_t)c * D_))[lane];
    float q0 = bflo(qw.x), q1 = bfhi(qw.x), q2 = bflo(qw.y), q3 = bfhi(qw.y);
    float d = q0*k0 + q1*k1 + q2*k2 + q3*k3;
    #pragma unroll
    for (int o = 32; o > 0; o >>= 1) d += __shfl_xor(d, o);
    float s = d * b2s;
    float pe = expf(s - m_row[c]) * linv_row[c];
    a0 += pe*q0; a1 += pe*q1; a2 += pe*q2; a3 += pe*q3;
  }
  float coef = -lam2 * 0.0625f;
  float4 o4; o4.x = coef*a0; o4.y = coef*a1; o4.z = coef*a2; o4.w = coef*a3;
  *(float4*)(dK2 + (size_t)r * D_ + (lane << 2)) = o4;
}

// ---------- order-3 by-c: online softmax + dQ3, wave per row ----------
__global__ __launch_bounds__(256) void e3_rowc(const ushort_t* __restrict__ Q3, const ushort_t* __restrict__ K3,
    const float* __restrict__ Tt, const int* __restrict__ cur_c, const unsigned* __restrict__ adj3c,
    float* __restrict__ dQ3, float* __restrict__ m_row, float* __restrict__ linv_row,
    float* __restrict__ accum, int N_, const float* __restrict__ b3p, const float* __restrict__ l3p)
{
  __shared__ float sbuf[4];
  int r = blockIdx.x * 4 + (threadIdx.x >> 6);
  int lane = threadIdx.x & 63;
  float b3s = fminf(softplus_f(*b3p), 5.0f) * 0.0625f;
  float lam3 = softplus_f(*l3p);
  int start = (r > 0) ? cur_c[r - 1] : 0;
  int end = cur_c[r];
  // per-lane slice: elements lane*8 .. lane*8+7 of the 512-dim row
  uint4 qw = ((const uint4*)(Q3 + (size_t)r * 2 * D_))[lane];
  float q[8] = {bflo(qw.x),bfhi(qw.x),bflo(qw.y),bfhi(qw.y),bflo(qw.z),bfhi(qw.z),bflo(qw.w),bfhi(qw.w)};
  float4 t0a = ((const float4*)(Tt))[2*lane], t0b = ((const float4*)(Tt))[2*lane+1];
  float4 t1a = ((const float4*)(Tt + 2*D_))[2*lane], t1b = ((const float4*)(Tt + 2*D_))[2*lane+1];
  float T0[8] = {t0a.x,t0a.y,t0a.z,t0a.w,t0b.x,t0b.y,t0b.z,t0b.w};
  float T1[8] = {t1a.x,t1a.y,t1a.z,t1a.w,t1b.x,t1b.y,t1b.z,t1b.w};
  float m = -1e30f, l = 0.f;
  float a[8] = {};
  for (int p = start; p < end; ++p){
    unsigned ent = adj3c[p];
    int u = ent & 32767, v = (ent >> 15) & 32767, tau = (ent >> 30) & 1;
    uint4 bw = ((const uint4*)(K3 + (size_t)u * 2 * D_))[lane];
    uint4 cw = ((const uint4*)(K3 + (size_t)v * 2 * D_))[lane];
    float kb[8] = {bflo(bw.x),bfhi(bw.x),bflo(bw.y),bfhi(bw.y),bflo(bw.z),bfhi(bw.z),bflo(bw.w),bfhi(bw.w)};
    float kc[8] = {bflo(cw.x),bfhi(cw.x),bflo(cw.y),bfhi(cw.y),bflo(cw.z),bfhi(cw.z),bflo(cw.w),bfhi(cw.w)};
    float prod[8];
    float d = 0.f;
    #pragma unroll
    for (int j = 0; j < 8; ++j){
      float tj = tau ? T1[j] : T0[j];
      prod[j] = kb[j] * kc[j] * tj;
      d += q[j] * prod[j];
    }
    #pragma unroll
    for (int o = 32; o > 0; o >>= 1) d += __shfl_xor(d, o);
    float s = d * b3s;
    float mn = fmaxf(m, s);
    float sc = expf(m - mn);
    float pt = expf(s - mn);
    l = l * sc + pt;
    #pragma unroll
    for (int j = 0; j < 8; ++j) a[j] = a[j]*sc + pt*prod[j];
    m = mn;
  }
  float lse = 0.f, linv = 0.f, coef = 0.f;
  if (end > start){ lse = m + logf(l); linv = 1.0f / l; coef = -lam3 * 0.0625f * linv; }
  float4 o0, o1;
  o0.x=coef*a[0]; o0.y=coef*a[1]; o0.z=coef*a[2]; o0.w=coef*a[3];
  o1.x=coef*a[4]; o1.y=coef*a[5]; o1.z=coef*a[6]; o1.w=coef*a[7];
  float* dst = dQ3 + (size_t)r * 2 * D_ + (lane << 3);
  *(float4*)dst = o0; *(float4*)(dst + 4) = o1;
  if (lane == 0){ m_row[r] = m; linv_row[r] = linv; sbuf[threadIdx.x >> 6] = lse; }
  __syncthreads();
  if (threadIdx.x == 0) atomicAdd(accum, sbuf[0] + sbuf[1] + sbuf[2] + sbuf[3]);
}

// ---------- order-3 incidence (u and v roles): dK3, wave per row ----------
__global__ __launch_bounds__(256) void e3_rowi(const ushort_t* __restrict__ Q3, const ushort_t* __restrict__ K3,
    const float* __restrict__ Tt, const int* __restrict__ cur_i, const unsigned* __restrict__ adj3i,
    float* __restrict__ dK3, const float* __restrict__ m_row, const float* __restrict__ linv_row,
    int N_, const float* __restrict__ b3p, const float* __restrict__ l3p)
{
  int r = blockIdx.x * 4 + (threadIdx.x >> 6);
  int lane = threadIdx.x & 63;
  float b3s = fminf(softplus_f(*b3p), 5.0f) * 0.0625f;
  float lam3 = softplus_f(*l3p);
  int start = (r > 0) ? cur_i[r - 1] : 0;
  int end = cur_i[r];
  uint4 rw = ((const uint4*)(K3 + (size_t)r * 2 * D_))[lane];
  float kr[8] = {bflo(rw.x),bfhi(rw.x),bflo(rw.y),bfhi(rw.y),bflo(rw.z),bfhi(rw.z),bflo(rw.w),bfhi(rw.w)};
  float4 t0a = ((const float4*)(Tt))[2*lane], t0b = ((const float4*)(Tt))[2*lane+1];
  float4 t1a = ((const float4*)(Tt + 2*D_))[2*lane], t1b = ((const float4*)(Tt + 2*D_))[2*lane+1];
  float T0[8] = {t0a.x,t0a.y,t0a.z,t0a.w,t0b.x,t0b.y,t0b.z,t0b.w};
  float T1[8] = {t1a.x,t1a.y,t1a.z,t1a.w,t1b.x,t1b.y,t1b.z,t1b.w};
  float a[8] = {};
  for (int p = start; p < end; ++p){
    unsigned ent = adj3i[p];
    int c = ent & 32767, o = (ent >> 15) & 32767, tau = (ent >> 30) & 1;
    uint4 qw = ((const uint4*)(Q3 + (size_t)c * 2 * D_))[lane];
    uint4 ow = ((const uint4*)(K3 + (size_t)o * 2 * D_))[lane];
    float q[8] = {bflo(qw.x),bfhi(qw.x),bflo(qw.y),bfhi(qw.y),bflo(qw.z),bfhi(qw.z),bflo(qw.w),bfhi(qw.w)};
    float ko[8] = {bflo(ow.x),bfhi(ow.x),bflo(ow.y),bfhi(ow.y),bflo(ow.z),bfhi(ow.z),bflo(ow.w),bfhi(ow.w)};
    float w[8];
    float d = 0.f;
    #pragma unroll
    for (int j = 0; j < 8; ++j){
      float tj = tau ? T1[j] : T0[j];
      w[j] = q[j] * ko[j] * tj;
      d += w[j] * kr[j];
    }
    #pragma unroll
    for (int o2 = 32; o2 > 0; o2 >>= 1) d += __shfl_xor(d, o2);
    float s = d * b3s;
    float pe = expf(s - m_row[c]) * linv_row[c];
    #pragma unroll
    for (int j = 0; j < 8; ++j) a[j] += pe * w[j];
  }
  float coef = -lam3 * 0.0625f;
  float4 o0, o1;
  o0.x=coef*a[0]; o0.y=coef*a[1]; o0.z=coef*a[2]; o0.w=coef*a[3];
  o1.x=coef*a[4]; o1.y=coef*a[5]; o1.z=coef*a[6]; o1.w=coef*a[7];
  float* dst = dK3 + (size_t)r * 2 * D_ + (lane << 3);
  *(float4*)dst = o0; *(float4*)(dst + 4) = o1;
}

// ---------- memory term ----------
__global__ __launch_bounds__(256) void mem_rows(float* __restrict__ Qm, const float* __restrict__ Km,
    float* __restrict__ lseM, const float* __restrict__ bmp, const float* __restrict__ lmp)
{
  __shared__ float sKm[KSLOT * D_];
  __shared__ float sq[D_];
  __shared__ float sS[KSLOT];
  int n = blockIdx.x, t = threadIdx.x;
  for (int i = t; i < KSLOT * D_ / 4; i += 256)
    ((float4*)sKm)[i] = ((const float4*)Km)[i];
  sq[t] = Qm[(size_t)n * D_ + t];
  __syncthreads();
  float bm = fminf(softplus_f(*bmp), 5.0f);
  int g = t >> 3, i = t & 7;
  float part = 0.f;
  int d0 = i * 32;
  #pragma unroll 8
  for (int d = d0; d < d0 + 32; ++d) part += sq[d] * sKm[g * D_ + d];
  part += __shfl_xor(part, 1); part += __shfl_xor(part, 2); part += __shfl_xor(part, 4);
  if (i == 0) sS[g] = part * bm * 0.0625f;
  __syncthreads();
  if (t < 32){
    float v = sS[t];
    float m = v;
    #pragma unroll
    for (int o = 16; o > 0; o >>= 1) m = fmaxf(m, __shfl_xor(m, o));
    float e = expf(v - m);
    float se = e;
    #pragma unroll
    for (int o = 16; o > 0; o >>= 1) se += __shfl_xor(se, o);
    sS[t] = e / se;
    if (t == 0) lseM[n] = m + logf(se);
  }
  __syncthreads();
  float acc = 0.f;
  #pragma unroll 8
  for (int k = 0; k < KSLOT; ++k) acc += sS[k] * sKm[k * D_ + t];
  float lam = softplus_f(*lmp);
  Qm[(size_t)n * D_ + t] = -lam * 0.0625f * acc;
}

// ---------- sum reduce ----------
__global__ __launch_bounds__(256) void reduce_sum(const float* __restrict__ v, int n, float* __restrict__ accum)
{
  __shared__ float sbuf[8];
  float acc = 0.f;
  for (int i = blockIdx.x * 256 + threadIdx.x; i < n; i += gridDim.x * 256) acc += v[i];
  float bs = block_reduce_sum(acc, sbuf);
  if (threadIdx.x == 0) atomicAdd(accum, bs);
}

// ---------- LN backward + clips + update ----------
__global__ __launch_bounds__(256) void ln_bwd_update(const float* __restrict__ X, const float* __restrict__ dG,
    const float* __restrict__ gamma, const float* __restrict__ mean, const float* __restrict__ rstd,
    const float* __restrict__ step_p, float* __restrict__ out)
{
  __shared__ float sbuf[8];
  int n = blockIdx.x, t = threadIdx.x;
  size_t idx = (size_t)n * D_ + t;
  float x = X[idx];
  float rs = rstd[n];
  float xh = (x - mean[n]) * rs;
  float dxh = dG[idx] * gamma[t];
  float s1 = block_reduce_sum(dxh, sbuf) * (1.0f / D_);
  float s2v = block_reduce_sum(dxh * xh, sbuf) * (1.0f / D_);
  float dx = rs * (dxh - s1 - xh * s2v);
  float gn2 = block_reduce_sum(dx * dx, sbuf);
  float gn = fmaxf(sqrtf(gn2), 1e-6f);
  float gsc = fminf(1.0f / gn, 1.0f);
  float stp = step_p[0] * 0.9999f;
  float xn = x - stp * gsc * dx;
  float sn2 = block_reduce_sum(xn * xn, sbuf);
  float sn = fmaxf(sqrtf(sn2), 1e-6f);
  float ssc = fminf(10.0f / sn, 1.0f);
  out[idx] = xn * ssc;
}

// ---------- final energy scalar ----------
__global__ void efinal(const float* __restrict__ accum, const float* l2p, const float* l3p, const float* lmp,
    const float* b2p, const float* b3p, const float* bmp, float* __restrict__ outE)
{
  float l2 = softplus_f(*l2p), l3 = softplus_f(*l3p), lm = softplus_f(*lmp);
  float b2 = fminf(softplus_f(*b2p), 5.0f);
  float b3 = fminf(softplus_f(*b3p), 5.0f);
  float bm = fminf(softplus_f(*bmp), 5.0f);
  *outE = -(l2 / b2) * accum[0] - (l3 / b3) * accum[1] - (lm / bm) * accum[2];
}

static inline void zfill(void* p, size_t nElems, hipStream_t stream){
  size_t n4 = nElems / 4;
  int blocks = (int)(((n4 + 255) / 256) < 16384 ? ((n4 + 255) / 256) : 16384);
  if (blocks < 1) blocks = 1;
  zerok<<<blocks, 256, 0, stream>>>((float4*)p, n4);
}

extern "C" void kernel_launch(void* const* d_in, const int* in_sizes, int n_in,
                              void* d_out, int out_size, void* d_ws, size_t ws_size,
                              hipStream_t stream)
{
  const float* X     = (const float*)d_in[0];
  const int*   c2    = (const int*)d_in[1];
  const int*   u2    = (const int*)d_in[2];
  const int*   c3    = (const int*)d_in[3];
  const int*   u3    = (const int*)d_in[4];
  const int*   v3    = (const int*)d_in[5];
  const int*   tt    = (const int*)d_in[6];
  const float* stepp = (const float*)d_in[7];
  const float* gamma = (const float*)d_in[8];
  const float* beta  = (const float*)d_in[9];
  const float* W_Q2  = (const float*)d_in[10];
  const float* W_K2  = (const float*)d_in[11];
  const float* W_Q3  = (const float*)d_in[12];
  const float* W_K3  = (const float*)d_in[13];
  const float* T_tau = (const float*)d_in[14];
  const float* W_Qm  = (const float*)d_in[15];
  const float* W_Km  = (const float*)d_in[16];
  const float* B_mem = (const float*)d_in[17];
  const float* l2p   = (const float*)d_in[18];
  const float* l3p   = (const float*)d_in[19];
  const float* lmp   = (const float*)d_in[20];
  const float* b2p   = (const float*)d_in[21];
  const float* b3p   = (const float*)d_in[22];
  const float* bmp   = (const float*)d_in[23];

  const int N  = in_sizes[0] / D_;
  const int NE = in_sizes[1];
  const int NT = in_sizes[3];
  const size_t ND = (size_t)N * D_;

  // ---- byte arena (~170 MB) ----
  char* base = (char*)d_ws;
  size_t off = 0;
  auto alloc = [&](size_t bytes) -> void* {
    void* p = base + off;
    off += (bytes + 255) & ~(size_t)255;
    return p;
  };
  float*    G     = (float*)   alloc(ND * 4);          // 32 MB
  ushort_t* Q3b   = (ushort_t*)alloc(ND * 2 * 2);      // 32 MB (doubles as Q2b)
  ushort_t* K3b   = (ushort_t*)alloc(ND * 2 * 2);      // 32 MB (doubles as K2b)
  float*    dbuf  = (float*)   alloc(ND * 2 * 4);      // 64 MB: Qm/dQm -> dQ2|dK2 -> dQ3 -> dK3
  int*      curc2 = (int*)     alloc((size_t)N * 4);
  int*      curu2 = (int*)     alloc((size_t)N * 4);
  int*      curc3 = (int*)     alloc((size_t)N * 4);
  int*      curi3 = (int*)     alloc((size_t)N * 4);
  int*      adjc_u= (int*)     alloc((size_t)NE * 4);  // 4 MB
  int*      adju_c= (int*)     alloc((size_t)NE * 4);  // 4 MB
  unsigned* adj3c = (unsigned*)alloc((size_t)NT * 4);
  unsigned* adj3i = (unsigned*)alloc((size_t)NT * 2 * 4);
  float*    m2r   = (float*)   alloc((size_t)N * 4);
  float*    li2r  = (float*)   alloc((size_t)N * 4);
  float*    m3r   = (float*)   alloc((size_t)N * 4);
  float*    li3r  = (float*)   alloc((size_t)N * 4);
  float*    Km    = (float*)   alloc((size_t)KSLOT * D_ * 4);
  float*    meanb = (float*)   alloc((size_t)N * 4);
  float*    rstdb = (float*)   alloc((size_t)N * 4);
  float*    lseM  = (float*)   alloc((size_t)N * 4);
  float*    accum = (float*)   alloc(64);

  float* out = (float*)d_out;     // out[0:ND] doubles as dG
  ushort_t* Q2b = Q3b;
  ushort_t* K2b = K3b;

  // zero counters
  zfill(curc2, N, stream); zfill(curu2, N, stream);
  zfill(curc3, N, stream); zfill(curi3, N, stream);
  zfill(accum, 16, stream);

  // 1. LN forward
  ln_fwd<<<N, 256, 0, stream>>>(X, gamma, beta, G, meanb, rstdb);

  // CSR build
  hist2<<<(NE + 255) / 256, 256, 0, stream>>>(c2, u2, curc2, curu2, NE);
  hist3<<<(NT + 255) / 256, 256, 0, stream>>>(c3, u3, v3, curc3, curi3, NT);
  scan_excl<<<1, 256, 0, stream>>>(curc2, N);
  scan_excl<<<1, 256, 0, stream>>>(curu2, N);
  scan_excl<<<1, 256, 0, stream>>>(curc3, N);
  scan_excl<<<1, 256, 0, stream>>>(curi3, N);
  scatter2<<<(NE + 255) / 256, 256, 0, stream>>>(c2, u2, curc2, curu2, adjc_u, adju_c, NE);
  scatter3<<<(NT + 255) / 256, 256, 0, stream>>>(c3, u3, v3, tt, curc3, curi3, adj3c, adj3i, NT);

  dim3 g256(D_ / 64, N / 64);
  dim3 g512(2 * D_ / 64, N / 64);

  // 2. memory term (dbuf = Qm then dQm)
  gemm_nn_f32<<<g256, 256, 0, stream>>>(G, W_Qm, dbuf, D_, D_);
  km_kernel<<<KSLOT, 256, 0, stream>>>(B_mem, W_Km, Km);
  mem_rows<<<N, 256, 0, stream>>>(dbuf, Km, lseM, bmp, lmp);
  reduce_sum<<<128, 256, 0, stream>>>(lseM, N, accum + 2);
  gemm_nt_f32<<<g256, 256, 0, stream>>>(dbuf, W_Qm, out, D_, D_, 0);  // dG = dQm W_Qm^T

  // 3. order-2
  gemm_nn_bf16<<<g256, 256, 0, stream>>>(G, W_Q2, Q2b, D_, D_);
  gemm_nn_bf16<<<g256, 256, 0, stream>>>(G, W_K2, K2b, D_, D_);
  e2_rowc<<<N / 4, 256, 0, stream>>>(Q2b, K2b, curc2, adjc_u, dbuf, m2r, li2r, accum + 0, N, b2p, l2p);
  e2_rowu<<<N / 4, 256, 0, stream>>>(Q2b, K2b, curu2, adju_c, dbuf + ND, m2r, li2r, N, b2p, l2p);
  gemm_nt_f32<<<g256, 256, 0, stream>>>(dbuf,      W_Q2, out, D_, D_, 1);
  gemm_nt_f32<<<g256, 256, 0, stream>>>(dbuf + ND, W_K2, out, D_, D_, 1);

  // 4. order-3 (Q3b/K3b overwrite Q2b/K2b — order-2 retired)
  gemm_nn_bf16<<<g512, 256, 0, stream>>>(G, W_Q3, Q3b, D_, 2 * D_);
  gemm_nn_bf16<<<g512, 256, 0, stream>>>(G, W_K3, K3b, D_, 2 * D_);
  e3_rowc<<<N / 4, 256, 0, stream>>>(Q3b, K3b, T_tau, curc3, adj3c, dbuf, m3r, li3r, accum + 1, N, b3p, l3p);
  gemm_nt_f32<<<g256, 256, 0, stream>>>(dbuf, W_Q3, out, 2 * D_, D_, 1);
  e3_rowi<<<N / 4, 256, 0, stream>>>(Q3b, K3b, T_tau, curi3, adj3i, dbuf, m3r, li3r, N, b3p, l3p);
  gemm_nt_f32<<<g256, 256, 0, stream>>>(dbuf, W_K3, out, 2 * D_, D_, 1);

  // 5. LN backward + clips + update
  ln_bwd_update<<<N, 256, 0, stream>>>(X, out, gamma, meanb, rstdb, stepp, out);

  // 6. energy scalar
  efinal<<<1, 1, 0, stream>>>(accum, l2p, l3p, lmp, b2p, b3p, bmp, out + ND);
}

// Round 4
// 1689.540 us; speedup vs baseline: 6.4222x; 1.4153x over previous
//
#include <hip/hip_runtime.h>
#include <math.h>

#define D_ 256
#define KSLOT 32
typedef unsigned short ushort_t;
typedef __attribute__((ext_vector_type(8))) short bf16x8;
typedef __attribute__((ext_vector_type(4))) float f32x4;

// ---------- helpers ----------
__device__ __forceinline__ float softplus_f(float x){
  return (x > 20.0f) ? x : log1pf(expf(x));
}
__device__ __forceinline__ float bflo(unsigned u){ return __uint_as_float(u << 16); }
__device__ __forceinline__ float bfhi(unsigned u){ return __uint_as_float(u & 0xFFFF0000u); }
__device__ __forceinline__ ushort_t f2b(float f){   // fp32 -> bf16 RNE
  unsigned u = __float_as_uint(f);
  unsigned r = u + 0x7FFFu + ((u >> 16) & 1u);
  return (ushort_t)(r >> 16);
}
__device__ __forceinline__ unsigned pack2(float a, float b){
  return (unsigned)f2b(a) | ((unsigned)f2b(b) << 16);
}
__device__ __forceinline__ float block_reduce_sum(float v, float* sbuf){
  #pragma unroll
  for (int o = 32; o > 0; o >>= 1) v += __shfl_xor(v, o);
  int t = threadIdx.x, wid = t >> 6, lane = t & 63;
  if (lane == 0) sbuf[wid] = v;
  __syncthreads();
  if (t == 0) sbuf[0] = sbuf[0] + sbuf[1] + sbuf[2] + sbuf[3];
  __syncthreads();
  float r = sbuf[0];
  __syncthreads();
  return r;
}

// ---------- zero fill ----------
__global__ __launch_bounds__(256) void zerok(float4* __restrict__ p, size_t n4){
  float4 z; z.x = z.y = z.z = z.w = 0.f;
  for (size_t i = (size_t)blockIdx.x * 256 + threadIdx.x; i < n4; i += (size_t)gridDim.x * 256)
    p[i] = z;
}

// ---------- layernorm forward -> bf16 G ----------
__global__ __launch_bounds__(256) void ln_fwd(const float* __restrict__ X, const float* __restrict__ gamma,
    const float* __restrict__ beta, ushort_t* __restrict__ Gb, float* __restrict__ mean, float* __restrict__ rstd)
{
  __shared__ float sbuf[8];
  int n = blockIdx.x, t = threadIdx.x;
  size_t idx = (size_t)n * D_ + t;
  float x = X[idx];
  float mu = block_reduce_sum(x, sbuf) * (1.0f / D_);
  float d = x - mu;
  float var = block_reduce_sum(d * d, sbuf) * (1.0f / D_);
  float rs = rsqrtf(var + 1e-5f);
  Gb[idx] = f2b(d * rs * gamma[t] + beta[t]);
  if (t == 0){ mean[n] = mu; rstd[n] = rs; }
}

// ---------- weight prep ----------
// Wt[m*Kdim + k] = bf16(W[k*Mdim + m])   (transpose for forward GEMMs)
__global__ __launch_bounds__(256) void wprep_t(const float* __restrict__ W, ushort_t* __restrict__ Wt,
    int Kdim, int Mdim)
{
  int idx = blockIdx.x * 256 + threadIdx.x;
  if (idx >= Kdim * Mdim) return;
  int m = idx / Kdim, k = idx - m * Kdim;
  Wt[idx] = f2b(W[(size_t)k * Mdim + m]);
}
// plain cast
__global__ __launch_bounds__(256) void wprep_c(const float* __restrict__ W, ushort_t* __restrict__ Wb, int n)
{
  int idx = blockIdx.x * 256 + threadIdx.x;
  if (idx >= n) return;
  Wb[idx] = f2b(W[idx]);
}

// ---------- MFMA GEMM: C[N,M] op= A[N,K] @ Bt[M,K]^T  (A,Bt bf16, K contiguous) ----------
// OUT_MODE: 0 = store fp32, 1 = accumulate fp32, 2 = store bf16
template<int OUT_MODE>
__global__ __launch_bounds__(256) void gemm_bt_mfma(const ushort_t* __restrict__ A,
    const ushort_t* __restrict__ Bt, void* __restrict__ C, int K, int M)
{
  __shared__ __align__(16) ushort_t As[128 * 32];
  __shared__ __align__(16) ushort_t Bs[128 * 32];
  int t = threadIdx.x;
  int wave = t >> 6, lane = t & 63;
  int row0 = blockIdx.y * 128;
  int col0 = blockIdx.x * 128;
  int wrow = (wave & 1) * 64;
  int wcol = (wave >> 1) * 64;
  f32x4 acc[4][4];
  #pragma unroll
  for (int i = 0; i < 4; ++i)
    #pragma unroll
    for (int j = 0; j < 4; ++j)
      acc[i][j] = (f32x4){0.f, 0.f, 0.f, 0.f};
  int srow = t >> 1;              // 0..127
  int soff = (t & 1) * 16;        // elem offset of this thread's 16-elem half-row
  const ushort_t* Ag = A + (size_t)(row0 + srow) * K + soff;
  const ushort_t* Bg = Bt + (size_t)(col0 + srow) * K + soff;
  ushort_t* Al = As + srow * 32 + soff;
  ushort_t* Bl = Bs + srow * 32 + soff;
  int lrow = lane & 15, lk = (lane >> 4) * 8;
  for (int k0 = 0; k0 < K; k0 += 32){
    uint4 av0 = *(const uint4*)(Ag + k0);
    uint4 av1 = *(const uint4*)(Ag + k0 + 8);
    uint4 bv0 = *(const uint4*)(Bg + k0);
    uint4 bv1 = *(const uint4*)(Bg + k0 + 8);
    __syncthreads();
    *(uint4*)Al = av0; *(uint4*)(Al + 8) = av1;
    *(uint4*)Bl = bv0; *(uint4*)(Bl + 8) = bv1;
    __syncthreads();
    bf16x8 af[4], bf_[4];
    #pragma unroll
    for (int i = 0; i < 4; ++i)
      af[i] = *(const bf16x8*)(As + (wrow + i * 16 + lrow) * 32 + lk);
    #pragma unroll
    for (int j = 0; j < 4; ++j)
      bf_[j] = *(const bf16x8*)(Bs + (wcol + j * 16 + lrow) * 32 + lk);
    #pragma unroll
    for (int i = 0; i < 4; ++i)
      #pragma unroll
      for (int j = 0; j < 4; ++j)
        acc[i][j] = __builtin_amdgcn_mfma_f32_16x16x32_bf16(af[i], bf_[j], acc[i][j], 0, 0, 0);
  }
  // epilogue: row = (lane>>4)*4 + reg (A index), col = lane&15 (B index)
  int rbase = row0 + wrow + (lane >> 4) * 4;
  int cbase = col0 + wcol + (lane & 15);
  #pragma unroll
  for (int i = 0; i < 4; ++i){
    #pragma unroll
    for (int r = 0; r < 4; ++r){
      size_t rowoff = (size_t)(rbase + i * 16 + r) * M;
      #pragma unroll
      for (int j = 0; j < 4; ++j){
        int col = cbase + j * 16;
        float v = acc[i][j][r];
        if (OUT_MODE == 0)      ((float*)C)[rowoff + col] = v;
        else if (OUT_MODE == 1) ((float*)C)[rowoff + col] += v;
        else                    ((ushort_t*)C)[rowoff + col] = f2b(v);
      }
    }
  }
}

// ---------- Km = B_mem @ W_Km (fp32, tiny) ----------
__global__ __launch_bounds__(256) void km_kernel(const float* __restrict__ Bm, const float* __restrict__ W,
    float* __restrict__ Km)
{
  __shared__ float sb[D_];
  int k = blockIdx.x, t = threadIdx.x;
  sb[t] = Bm[(size_t)k * D_ + t];
  __syncthreads();
  float acc = 0.f;
  for (int d = 0; d < D_; ++d) acc += sb[d] * W[(size_t)d * D_ + t];
  Km[(size_t)k * D_ + t] = acc;
}

// ---------- CSR build ----------
__global__ __launch_bounds__(256) void hist2(const int* __restrict__ c2, const int* __restrict__ u2,
    int* __restrict__ cnt_c, int* __restrict__ cnt_u, int NE_)
{
  int e = blockIdx.x * 256 + threadIdx.x;
  if (e >= NE_) return;
  atomicAdd(cnt_c + c2[e], 1);
  atomicAdd(cnt_u + u2[e], 1);
}
__global__ __launch_bounds__(256) void hist3(const int* __restrict__ c3, const int* __restrict__ u3,
    const int* __restrict__ v3, int* __restrict__ cnt_c, int* __restrict__ cnt_i, int NT_)
{
  int e = blockIdx.x * 256 + threadIdx.x;
  if (e >= NT_) return;
  atomicAdd(cnt_c + c3[e], 1);
  atomicAdd(cnt_i + u3[e], 1);
  atomicAdd(cnt_i + v3[e], 1);
}
__global__ __launch_bounds__(256) void scan_excl(int* __restrict__ d, int n)
{
  __shared__ int wsum[4];
  __shared__ int carry;
  int t = threadIdx.x, lane = t & 63, wid = t >> 6;
  if (t == 0) carry = 0;
  __syncthreads();
  for (int base = 0; base < n; base += 256){
    int v = d[base + t];
    int x = v;
    #pragma unroll
    for (int o = 1; o < 64; o <<= 1){
      int y = __shfl_up(x, o);
      if (lane >= o) x += y;
    }
    if (lane == 63) wsum[wid] = x;
    __syncthreads();
    int woff = 0;
    for (int i = 0; i < wid; ++i) woff += wsum[i];
    int excl = carry + woff + x - v;
    d[base + t] = excl;
    __syncthreads();
    if (t == 255) carry = carry + woff + x;
    __syncthreads();
  }
}
__global__ __launch_bounds__(256) void scatter2(const int* __restrict__ c2, const int* __restrict__ u2,
    int* __restrict__ cur_c, int* __restrict__ cur_u, int* __restrict__ adjc_u, int* __restrict__ adju_c, int NE_)
{
  int e = blockIdx.x * 256 + threadIdx.x;
  if (e >= NE_) return;
  int c = c2[e], u = u2[e];
  int pc = atomicAdd(cur_c + c, 1);
  adjc_u[pc] = u;
  int pu = atomicAdd(cur_u + u, 1);
  adju_c[pu] = c;
}
__global__ __launch_bounds__(256) void scatter3(const int* __restrict__ c3, const int* __restrict__ u3,
    const int* __restrict__ v3, const int* __restrict__ tt, int* __restrict__ cur_c, int* __restrict__ cur_i,
    unsigned* __restrict__ adj3c, unsigned* __restrict__ adj3i, int NT_)
{
  int e = blockIdx.x * 256 + threadIdx.x;
  if (e >= NT_) return;
  int c = c3[e], u = u3[e], v = v3[e], tau = tt[e];
  int pc = atomicAdd(cur_c + c, 1);
  adj3c[pc] = (unsigned)u | ((unsigned)v << 15) | ((unsigned)tau << 30);
  int pu = atomicAdd(cur_i + u, 1);
  adj3i[pu] = (unsigned)c | ((unsigned)v << 15) | ((unsigned)tau << 30);
  int pv = atomicAdd(cur_i + v, 1);
  adj3i[pv] = (unsigned)c | ((unsigned)u << 15) | ((unsigned)tau << 30);
}

// ---------- order-2 by-c: online softmax + dQ2 (bf16 out), wave per row ----------
__global__ __launch_bounds__(256) void e2_rowc(const ushort_t* __restrict__ Q2, const ushort_t* __restrict__ K2,
    const int* __restrict__ cur_c, const int* __restrict__ adjc_u, ushort_t* __restrict__ dQ2,
    float* __restrict__ m_row, float* __restrict__ linv_row, float* __restrict__ accum, int N_,
    const float* __restrict__ b2p, const float* __restrict__ l2p)
{
  __shared__ float sbuf[4];
  int r = blockIdx.x * 4 + (threadIdx.x >> 6);
  int lane = threadIdx.x & 63;
  float b2s = fminf(softplus_f(*b2p), 5.0f) * 0.0625f;
  float lam2 = softplus_f(*l2p);
  int start = (r > 0) ? cur_c[r - 1] : 0;
  int end = cur_c[r];
  uint2 qw = ((const uint2*)(Q2 + (size_t)r * D_))[lane];
  float q0 = bflo(qw.x), q1 = bfhi(qw.x), q2 = bflo(qw.y), q3 = bfhi(qw.y);
  float m = -1e30f, l = 0.f;
  float a0 = 0.f, a1 = 0.f, a2 = 0.f, a3 = 0.f;
  for (int p = start; p < end; ++p){
    int u = adjc_u[p];
    uint2 kw = ((const uint2*)(K2 + (size_t)u * D_))[lane];
    float k0 = bflo(kw.x), k1 = bfhi(kw.x), k2 = bflo(kw.y), k3 = bfhi(kw.y);
    float d = q0*k0 + q1*k1 + q2*k2 + q3*k3;
    #pragma unroll
    for (int o = 32; o > 0; o >>= 1) d += __shfl_xor(d, o);
    float s = d * b2s;
    float mn = fmaxf(m, s);
    float sc = expf(m - mn);
    float pt = expf(s - mn);
    l = l * sc + pt;
    a0 = a0*sc + pt*k0; a1 = a1*sc + pt*k1; a2 = a2*sc + pt*k2; a3 = a3*sc + pt*k3;
    m = mn;
  }
  float lse = 0.f, linv = 0.f, coef = 0.f;
  if (end > start){ lse = m + logf(l); linv = 1.0f / l; coef = -lam2 * 0.0625f * linv; }
  uint2 o2; o2.x = pack2(coef*a0, coef*a1); o2.y = pack2(coef*a2, coef*a3);
  *(uint2*)(dQ2 + (size_t)r * D_ + (lane << 2)) = o2;
  if (lane == 0){ m_row[r] = m; linv_row[r] = linv; sbuf[threadIdx.x >> 6] = lse; }
  __syncthreads();
  if (threadIdx.x == 0) atomicAdd(accum, sbuf[0] + sbuf[1] + sbuf[2] + sbuf[3]);
}

// ---------- order-2 by-u: dK2 (bf16 out), wave per row ----------
__global__ __launch_bounds__(256) void e2_rowu(const ushort_t* __restrict__ Q2, const ushort_t* __restrict__ K2,
    const int* __restrict__ cur_u, const int* __restrict__ adju_c, ushort_t* __restrict__ dK2,
    const float* __restrict__ m_row, const float* __restrict__ linv_row, int N_,
    const float* __restrict__ b2p, const float* __restrict__ l2p)
{
  int r = blockIdx.x * 4 + (threadIdx.x >> 6);
  int lane = threadIdx.x & 63;
  float b2s = fminf(softplus_f(*b2p), 5.0f) * 0.0625f;
  float lam2 = softplus_f(*l2p);
  int start = (r > 0) ? cur_u[r - 1] : 0;
  int end = cur_u[r];
  uint2 kw = ((const uint2*)(K2 + (size_t)r * D_))[lane];
  float k0 = bflo(kw.x), k1 = bfhi(kw.x), k2 = bflo(kw.y), k3 = bfhi(kw.y);
  float a0 = 0.f, a1 = 0.f, a2 = 0.f, a3 = 0.f;
  for (int p = start; p < end; ++p){
    int c = adju_c[p];
    uint2 qw = ((const uint2*)(Q2 + (size_t)c * D_))[lane];
    float q0 = bflo(qw.x), q1 = bfhi(qw.x), q2 = bflo(qw.y), q3 = bfhi(qw.y);
    float d = q0*k0 + q1*k1 + q2*k2 + q3*k3;
    #pragma unroll
    for (int o = 32; o > 0; o >>= 1) d += __shfl_xor(d, o);
    float s = d * b2s;
    float pe = expf(s - m_row[c]) * linv_row[c];
    a0 += pe*q0; a1 += pe*q1; a2 += pe*q2; a3 += pe*q3;
  }
  float coef = -lam2 * 0.0625f;
  uint2 o2; o2.x = pack2(coef*a0, coef*a1); o2.y = pack2(coef*a2, coef*a3);
  *(uint2*)(dK2 + (size_t)r * D_ + (lane << 2)) = o2;
}

// ---------- order-3 by-c: online softmax + dQ3 (bf16 out), wave per row ----------
__global__ __launch_bounds__(256) void e3_rowc(const ushort_t* __restrict__ Q3, const ushort_t* __restrict__ K3,
    const float* __restrict__ Tt, const int* __restrict__ cur_c, const unsigned* __restrict__ adj3c,
    ushort_t* __restrict__ dQ3, float* __restrict__ m_row, float* __restrict__ linv_row,
    float* __restrict__ accum, int N_, const float* __restrict__ b3p, const float* __restrict__ l3p)
{
  __shared__ float sbuf[4];
  int r = blockIdx.x * 4 + (threadIdx.x >> 6);
  int lane = threadIdx.x & 63;
  float b3s = fminf(softplus_f(*b3p), 5.0f) * 0.0625f;
  float lam3 = softplus_f(*l3p);
  int start = (r > 0) ? cur_c[r - 1] : 0;
  int end = cur_c[r];
  uint4 qw = ((const uint4*)(Q3 + (size_t)r * 2 * D_))[lane];
  float q[8] = {bflo(qw.x),bfhi(qw.x),bflo(qw.y),bfhi(qw.y),bflo(qw.z),bfhi(qw.z),bflo(qw.w),bfhi(qw.w)};
  float4 t0a = ((const float4*)(Tt))[2*lane], t0b = ((const float4*)(Tt))[2*lane+1];
  float4 t1a = ((const float4*)(Tt + 2*D_))[2*lane], t1b = ((const float4*)(Tt + 2*D_))[2*lane+1];
  float T0[8] = {t0a.x,t0a.y,t0a.z,t0a.w,t0b.x,t0b.y,t0b.z,t0b.w};
  float T1[8] = {t1a.x,t1a.y,t1a.z,t1a.w,t1b.x,t1b.y,t1b.z,t1b.w};
  float m = -1e30f, l = 0.f;
  float a[8] = {};
  for (int p = start; p < end; ++p){
    unsigned ent = adj3c[p];
    int u = ent & 32767, v = (ent >> 15) & 32767, tau = (ent >> 30) & 1;
    uint4 bw = ((const uint4*)(K3 + (size_t)u * 2 * D_))[lane];
    uint4 cw = ((const uint4*)(K3 + (size_t)v * 2 * D_))[lane];
    float kb[8] = {bflo(bw.x),bfhi(bw.x),bflo(bw.y),bfhi(bw.y),bflo(bw.z),bfhi(bw.z),bflo(bw.w),bfhi(bw.w)};
    float kc[8] = {bflo(cw.x),bfhi(cw.x),bflo(cw.y),bfhi(cw.y),bflo(cw.z),bfhi(cw.z),bflo(cw.w),bfhi(cw.w)};
    float prod[8];
    float d = 0.f;
    #pragma unroll
    for (int j = 0; j < 8; ++j){
      float tj = tau ? T1[j] : T0[j];
      prod[j] = kb[j] * kc[j] * tj;
      d += q[j] * prod[j];
    }
    #pragma unroll
    for (int o = 32; o > 0; o >>= 1) d += __shfl_xor(d, o);
    float s = d * b3s;
    float mn = fmaxf(m, s);
    float sc = expf(m - mn);
    float pt = expf(s - mn);
    l = l * sc + pt;
    #pragma unroll
    for (int j = 0; j < 8; ++j) a[j] = a[j]*sc + pt*prod[j];
    m = mn;
  }
  float lse = 0.f, linv = 0.f, coef = 0.f;
  if (end > start){ lse = m + logf(l); linv = 1.0f / l; coef = -lam3 * 0.0625f * linv; }
  uint4 o4;
  o4.x = pack2(coef*a[0], coef*a[1]); o4.y = pack2(coef*a[2], coef*a[3]);
  o4.z = pack2(coef*a[4], coef*a[5]); o4.w = pack2(coef*a[6], coef*a[7]);
  *(uint4*)(dQ3 + (size_t)r * 2 * D_ + (lane << 3)) = o4;
  if (lane == 0){ m_row[r] = m; linv_row[r] = linv; sbuf[threadIdx.x >> 6] = lse; }
  __syncthreads();
  if (threadIdx.x == 0) atomicAdd(accum, sbuf[0] + sbuf[1] + sbuf[2] + sbuf[3]);
}

// ---------- order-3 incidence: dK3 (bf16 out), wave per row ----------
__global__ __launch_bounds__(256) void e3_rowi(const ushort_t* __restrict__ Q3, const ushort_t* __restrict__ K3,
    const float* __restrict__ Tt, const int* __restrict__ cur_i, const unsigned* __restrict__ adj3i,
    ushort_t* __restrict__ dK3, const float* __restrict__ m_row, const float* __restrict__ linv_row,
    int N_, const float* __restrict__ b3p, const float* __restrict__ l3p)
{
  int r = blockIdx.x * 4 + (threadIdx.x >> 6);
  int lane = threadIdx.x & 63;
  float b3s = fminf(softplus_f(*b3p), 5.0f) * 0.0625f;
  float lam3 = softplus_f(*l3p);
  int start = (r > 0) ? cur_i[r - 1] : 0;
  int end = cur_i[r];
  uint4 rw = ((const uint4*)(K3 + (size_t)r * 2 * D_))[lane];
  float kr[8] = {bflo(rw.x),bfhi(rw.x),bflo(rw.y),bfhi(rw.y),bflo(rw.z),bfhi(rw.z),bflo(rw.w),bfhi(rw.w)};
  float4 t0a = ((const float4*)(Tt))[2*lane], t0b = ((const float4*)(Tt))[2*lane+1];
  float4 t1a = ((const float4*)(Tt + 2*D_))[2*lane], t1b = ((const float4*)(Tt + 2*D_))[2*lane+1];
  float T0[8] = {t0a.x,t0a.y,t0a.z,t0a.w,t0b.x,t0b.y,t0b.z,t0b.w};
  float T1[8] = {t1a.x,t1a.y,t1a.z,t1a.w,t1b.x,t1b.y,t1b.z,t1b.w};
  float a[8] = {};
  for (int p = start; p < end; ++p){
    unsigned ent = adj3i[p];
    int c = ent & 32767, o = (ent >> 15) & 32767, tau = (ent >> 30) & 1;
    uint4 qw = ((const uint4*)(Q3 + (size_t)c * 2 * D_))[lane];
    uint4 ow = ((const uint4*)(K3 + (size_t)o * 2 * D_))[lane];
    float q[8] = {bflo(qw.x),bfhi(qw.x),bflo(qw.y),bfhi(qw.y),bflo(qw.z),bfhi(qw.z),bflo(qw.w),bfhi(qw.w)};
    float ko[8] = {bflo(ow.x),bfhi(ow.x),bflo(ow.y),bfhi(ow.y),bflo(ow.z),bfhi(ow.z),bflo(ow.w),bfhi(ow.w)};
    float w[8];
    float d = 0.f;
    #pragma unroll
    for (int j = 0; j < 8; ++j){
      float tj = tau ? T1[j] : T0[j];
      w[j] = q[j] * ko[j] * tj;
      d += w[j] * kr[j];
    }
    #pragma unroll
    for (int o2 = 32; o2 > 0; o2 >>= 1) d += __shfl_xor(d, o2);
    float s = d * b3s;
    float pe = expf(s - m_row[c]) * linv_row[c];
    #pragma unroll
    for (int j = 0; j < 8; ++j) a[j] += pe * w[j];
  }
  float coef = -lam3 * 0.0625f;
  uint4 o4;
  o4.x = pack2(coef*a[0], coef*a[1]); o4.y = pack2(coef*a[2], coef*a[3]);
  o4.z = pack2(coef*a[4], coef*a[5]); o4.w = pack2(coef*a[6], coef*a[7]);
  *(uint4*)(dK3 + (size_t)r * 2 * D_ + (lane << 3)) = o4;
}

// ---------- memory term: conflict-free LDS (stride 264, interleaved d) ----------
__global__ __launch_bounds__(256) void mem_rows(const float* __restrict__ Qm, const float* __restrict__ Km,
    ushort_t* __restrict__ dQmb, float* __restrict__ lseM, const float* __restrict__ bmp,
    const float* __restrict__ lmp)
{
  __shared__ float sKm[KSLOT * 264];
  __shared__ float sq[D_];
  __shared__ float sS[KSLOT];
  int n = blockIdx.x, t = threadIdx.x;
  for (int idx = t; idx < KSLOT * D_; idx += 256){
    int k = idx >> 8, d = idx & 255;
    sKm[k * 264 + d] = Km[idx];
  }
  sq[t] = Qm[(size_t)n * D_ + t];
  __syncthreads();
  float bm = fminf(softplus_f(*bmp), 5.0f);
  int g = t >> 3, i = t & 7;
  float part = 0.f;
  #pragma unroll
  for (int s = 0; s < 32; ++s){
    int d = i + (s << 3);          // interleaved slice: bank = (8g + i) distinct per half-wave
    part += sq[d] * sKm[g * 264 + d];
  }
  part += __shfl_xor(part, 1); part += __shfl_xor(part, 2); part += __shfl_xor(part, 4);
  if (i == 0) sS[g] = part * bm * 0.0625f;
  __syncthreads();
  if (t < 32){
    float v = sS[t];
    float m = v;
    #pragma unroll
    for (int o = 16; o > 0; o >>= 1) m = fmaxf(m, __shfl_xor(m, o));
    float e = expf(v - m);
    float se = e;
    #pragma unroll
    for (int o = 16; o > 0; o >>= 1) se += __shfl_xor(se, o);
    sS[t] = e / se;
    if (t == 0) lseM[n] = m + logf(se);
  }
  __syncthreads();
  float acc = 0.f;
  #pragma unroll 8
  for (int k = 0; k < KSLOT; ++k) acc += sS[k] * sKm[k * 264 + t];
  float lam = softplus_f(*lmp);
  dQmb[(size_t)n * D_ + t] = f2b(-lam * 0.0625f * acc);
}

// ---------- sum reduce ----------
__global__ __launch_bounds__(256) void reduce_sum(const float* __restrict__ v, int n, float* __restrict__ accum)
{
  __shared__ float sbuf[8];
  float acc = 0.f;
  for (int i = blockIdx.x * 256 + threadIdx.x; i < n; i += gridDim.x * 256) acc += v[i];
  float bs = block_reduce_sum(acc, sbuf);
  if (threadIdx.x == 0) atomicAdd(accum, bs);
}

// ---------- LN backward + clips + update ----------
__global__ __launch_bounds__(256) void ln_bwd_update(const float* __restrict__ X, const float* __restrict__ dG,
    const float* __restrict__ gamma, const float* __restrict__ mean, const float* __restrict__ rstd,
    const float* __restrict__ step_p, float* __restrict__ out)
{
  __shared__ float sbuf[8];
  int n = blockIdx.x, t = threadIdx.x;
  size_t idx = (size_t)n * D_ + t;
  float x = X[idx];
  float rs = rstd[n];
  float xh = (x - mean[n]) * rs;
  float dxh = dG[idx] * gamma[t];
  float s1 = block_reduce_sum(dxh, sbuf) * (1.0f / D_);
  float s2v = block_reduce_sum(dxh * xh, sbuf) * (1.0f / D_);
  float dx = rs * (dxh - s1 - xh * s2v);
  float gn2 = block_reduce_sum(dx * dx, sbuf);
  float gn = fmaxf(sqrtf(gn2), 1e-6f);
  float gsc = fminf(1.0f / gn, 1.0f);
  float stp = step_p[0] * 0.9999f;
  float xn = x - stp * gsc * dx;
  float sn2 = block_reduce_sum(xn * xn, sbuf);
  float sn = fmaxf(sqrtf(sn2), 1e-6f);
  float ssc = fminf(10.0f / sn, 1.0f);
  out[idx] = xn * ssc;
}

// ---------- final energy scalar ----------
__global__ void efinal(const float* __restrict__ accum, const float* l2p, const float* l3p, const float* lmp,
    const float* b2p, const float* b3p, const float* bmp, float* __restrict__ outE)
{
  float l2 = softplus_f(*l2p), l3 = softplus_f(*l3p), lm = softplus_f(*lmp);
  float b2 = fminf(softplus_f(*b2p), 5.0f);
  float b3 = fminf(softplus_f(*b3p), 5.0f);
  float bm = fminf(softplus_f(*bmp), 5.0f);
  *outE = -(l2 / b2) * accum[0] - (l3 / b3) * accum[1] - (lm / bm) * accum[2];
}

static inline void zfill(void* p, size_t nElems, hipStream_t stream){
  size_t n4 = nElems / 4;
  int blocks = (int)(((n4 + 255) / 256) < 16384 ? ((n4 + 255) / 256) : 16384);
  if (blocks < 1) blocks = 1;
  zerok<<<blocks, 256, 0, stream>>>((float4*)p, n4);
}

extern "C" void kernel_launch(void* const* d_in, const int* in_sizes, int n_in,
                              void* d_out, int out_size, void* d_ws, size_t ws_size,
                              hipStream_t stream)
{
  const float* X     = (const float*)d_in[0];
  const int*   c2    = (const int*)d_in[1];
  const int*   u2    = (const int*)d_in[2];
  const int*   c3    = (const int*)d_in[3];
  const int*   u3    = (const int*)d_in[4];
  const int*   v3    = (const int*)d_in[5];
  const int*   tt    = (const int*)d_in[6];
  const float* stepp = (const float*)d_in[7];
  const float* gamma = (const float*)d_in[8];
  const float* beta  = (const float*)d_in[9];
  const float* W_Q2  = (const float*)d_in[10];
  const float* W_K2  = (const float*)d_in[11];
  const float* W_Q3  = (const float*)d_in[12];
  const float* W_K3  = (const float*)d_in[13];
  const float* T_tau = (const float*)d_in[14];
  const float* W_Qm  = (const float*)d_in[15];
  const float* W_Km  = (const float*)d_in[16];
  const float* B_mem = (const float*)d_in[17];
  const float* l2p   = (const float*)d_in[18];
  const float* l3p   = (const float*)d_in[19];
  const float* lmp   = (const float*)d_in[20];
  const float* b2p   = (const float*)d_in[21];
  const float* b3p   = (const float*)d_in[22];
  const float* bmp   = (const float*)d_in[23];

  const int N  = in_sizes[0] / D_;
  const int NE = in_sizes[1];
  const int NT = in_sizes[3];
  const size_t ND = (size_t)N * D_;

  // ---- byte arena ----
  char* base = (char*)d_ws;
  size_t off = 0;
  auto alloc = [&](size_t bytes) -> void* {
    void* p = base + off;
    off += (bytes + 255) & ~(size_t)255;
    return p;
  };
  ushort_t* Gb    = (ushort_t*)alloc(ND * 2);          // 16 MB
  ushort_t* Q3b   = (ushort_t*)alloc(ND * 2 * 2);      // 32 MB (doubles as Q2b)
  ushort_t* K3b   = (ushort_t*)alloc(ND * 2 * 2);      // 32 MB (doubles as K2b)
  float*    dbuf  = (float*)   alloc(ND * 2 * 4);      // 64 MB, phase-multiplexed
  int*      curc2 = (int*)     alloc((size_t)N * 4);
  int*      curu2 = (int*)     alloc((size_t)N * 4);
  int*      curc3 = (int*)     alloc((size_t)N * 4);
  int*      curi3 = (int*)     alloc((size_t)N * 4);
  int*      adjc_u= (int*)     alloc((size_t)NE * 4);
  int*      adju_c= (int*)     alloc((size_t)NE * 4);
  unsigned* adj3c = (unsigned*)alloc((size_t)NT * 4);
  unsigned* adj3i = (unsigned*)alloc((size_t)NT * 2 * 4);
  float*    m2r   = (float*)   alloc((size_t)N * 4);
  float*    li2r  = (float*)   alloc((size_t)N * 4);
  float*    m3r   = (float*)   alloc((size_t)N * 4);
  float*    li3r  = (float*)   alloc((size_t)N * 4);
  float*    Km    = (float*)   alloc((size_t)KSLOT * D_ * 4);
  float*    meanb = (float*)   alloc((size_t)N * 4);
  float*    rstdb = (float*)   alloc((size_t)N * 4);
  float*    lseM  = (float*)   alloc((size_t)N * 4);
  float*    accum = (float*)   alloc(64);
  // bf16 weights: forward (transposed [M,K]) and backward (row-major [D,M])
  ushort_t* Wt_Q2 = (ushort_t*)alloc((size_t)D_ * D_ * 2);
  ushort_t* Wt_K2 = (ushort_t*)alloc((size_t)D_ * D_ * 2);
  ushort_t* Wt_Q3 = (ushort_t*)alloc((size_t)D_ * 2 * D_ * 2);
  ushort_t* Wt_K3 = (ushort_t*)alloc((size_t)D_ * 2 * D_ * 2);
  ushort_t* Wt_Qm = (ushort_t*)alloc((size_t)D_ * D_ * 2);
  ushort_t* Wb_Q2 = (ushort_t*)alloc((size_t)D_ * D_ * 2);
  ushort_t* Wb_K2 = (ushort_t*)alloc((size_t)D_ * D_ * 2);
  ushort_t* Wb_Q3 = (ushort_t*)alloc((size_t)D_ * 2 * D_ * 2);
  ushort_t* Wb_K3 = (ushort_t*)alloc((size_t)D_ * 2 * D_ * 2);
  ushort_t* Wb_Qm = (ushort_t*)alloc((size_t)D_ * D_ * 2);

  float* out = (float*)d_out;     // out[0:ND] doubles as dG
  ushort_t* Q2b = Q3b;
  ushort_t* K2b = K3b;
  // phase-multiplexed views of dbuf
  float*    Qm    = dbuf;                               // mem phase (fp32, 32 MB)
  ushort_t* dQmb  = (ushort_t*)(dbuf + ND);             // mem phase (bf16, 16 MB)
  ushort_t* dQ2b  = (ushort_t*)dbuf;                    // order-2 phase
  ushort_t* dK2b  = (ushort_t*)dbuf + ND;
  ushort_t* dQ3b  = (ushort_t*)dbuf;                    // order-3 phase
  ushort_t* dK3b  = (ushort_t*)dbuf + ND * 2;

  // zero counters
  zfill(curc2, N, stream); zfill(curu2, N, stream);
  zfill(curc3, N, stream); zfill(curi3, N, stream);
  zfill(accum, 16, stream);

  // 1. LN forward (bf16 G)
  ln_fwd<<<N, 256, 0, stream>>>(X, gamma, beta, Gb, meanb, rstdb);

  // weight prep
  int n64k = (D_ * D_ + 255) / 256, n128k = (D_ * 2 * D_ + 255) / 256;
  wprep_t<<<n64k, 256, 0, stream>>>(W_Q2, Wt_Q2, D_, D_);
  wprep_t<<<n64k, 256, 0, stream>>>(W_K2, Wt_K2, D_, D_);
  wprep_t<<<n128k, 256, 0, stream>>>(W_Q3, Wt_Q3, D_, 2 * D_);
  wprep_t<<<n128k, 256, 0, stream>>>(W_K3, Wt_K3, D_, 2 * D_);
  wprep_t<<<n64k, 256, 0, stream>>>(W_Qm, Wt_Qm, D_, D_);
  wprep_c<<<n64k, 256, 0, stream>>>(W_Q2, Wb_Q2, D_ * D_);
  wprep_c<<<n64k, 256, 0, stream>>>(W_K2, Wb_K2, D_ * D_);
  wprep_c<<<n128k, 256, 0, stream>>>(W_Q3, Wb_Q3, D_ * 2 * D_);
  wprep_c<<<n128k, 256, 0, stream>>>(W_K3, Wb_K3, D_ * 2 * D_);
  wprep_c<<<n64k, 256, 0, stream>>>(W_Qm, Wb_Qm, D_ * D_);

  // CSR build
  hist2<<<(NE + 255) / 256, 256, 0, stream>>>(c2, u2, curc2, curu2, NE);
  hist3<<<(NT + 255) / 256, 256, 0, stream>>>(c3, u3, v3, curc3, curi3, NT);
  scan_excl<<<1, 256, 0, stream>>>(curc2, N);
  scan_excl<<<1, 256, 0, stream>>>(curu2, N);
  scan_excl<<<1, 256, 0, stream>>>(curc3, N);
  scan_excl<<<1, 256, 0, stream>>>(curi3, N);
  scatter2<<<(NE + 255) / 256, 256, 0, stream>>>(c2, u2, curc2, curu2, adjc_u, adju_c, NE);
  scatter3<<<(NT + 255) / 256, 256, 0, stream>>>(c3, u3, v3, tt, curc3, curi3, adj3c, adj3i, NT);

  dim3 gm256(D_ / 128, N / 128);        // M=256 tiles
  dim3 gm512(2 * D_ / 128, N / 128);    // M=512 tiles

  // 2. memory term
  gemm_bt_mfma<0><<<gm256, 256, 0, stream>>>(Gb, Wt_Qm, Qm, D_, D_);
  km_kernel<<<KSLOT, 256, 0, stream>>>(B_mem, W_Km, Km);
  mem_rows<<<N, 256, 0, stream>>>(Qm, Km, dQmb, lseM, bmp, lmp);
  reduce_sum<<<128, 256, 0, stream>>>(lseM, N, accum + 2);
  gemm_bt_mfma<0><<<gm256, 256, 0, stream>>>(dQmb, Wb_Qm, out, D_, D_);    // dG = dQm W_Qm^T

  // 3. order-2
  gemm_bt_mfma<2><<<gm256, 256, 0, stream>>>(Gb, Wt_Q2, Q2b, D_, D_);
  gemm_bt_mfma<2><<<gm256, 256, 0, stream>>>(Gb, Wt_K2, K2b, D_, D_);
  e2_rowc<<<N / 4, 256, 0, stream>>>(Q2b, K2b, curc2, adjc_u, dQ2b, m2r, li2r, accum + 0, N, b2p, l2p);
  e2_rowu<<<N / 4, 256, 0, stream>>>(Q2b, K2b, curu2, adju_c, dK2b, m2r, li2r, N, b2p, l2p);
  gemm_bt_mfma<1><<<gm256, 256, 0, stream>>>(dQ2b, Wb_Q2, out, D_, D_);
  gemm_bt_mfma<1><<<gm256, 256, 0, stream>>>(dK2b, Wb_K2, out, D_, D_);

  // 4. order-3 (Q3b/K3b overwrite Q2b/K2b — order-2 retired)
  gemm_bt_mfma<2><<<gm512, 256, 0, stream>>>(Gb, Wt_Q3, Q3b, D_, 2 * D_);
  gemm_bt_mfma<2><<<gm512, 256, 0, stream>>>(Gb, Wt_K3, K3b, D_, 2 * D_);
  e3_rowc<<<N / 4, 256, 0, stream>>>(Q3b, K3b, T_tau, curc3, adj3c, dQ3b, m3r, li3r, accum + 1, N, b3p, l3p);
  gemm_bt_mfma<1><<<gm256, 256, 0, stream>>>(dQ3b, Wb_Q3, out, 2 * D_, D_);
  e3_rowi<<<N / 4, 256, 0, stream>>>(Q3b, K3b, T_tau, curi3, adj3i, dK3b, m3r, li3r, N, b3p, l3p);
  gemm_bt_mfma<1><<<gm256, 256, 0, stream>>>(dK3b, Wb_K3, out, 2 * D_, D_);

  // 5. LN backward + clips + update
  ln_bwd_update<<<N, 256, 0, stream>>>(X, out, gamma, meanb, rstdb, stepp, out);

  // 6. energy scalar
  efinal<<<1, 1, 0, stream>>>(accum, l2p, l3p, lmp, b2p, b3p, bmp, out + ND);
}

// Round 5
// 1518.781 us; speedup vs baseline: 7.1442x; 1.1124x over previous
//
#include <hip/hip_runtime.h>
#include <math.h>

#define D_ 256
#define KSLOT 32
typedef unsigned short ushort_t;
typedef __attribute__((ext_vector_type(8))) short bf16x8;
typedef __attribute__((ext_vector_type(4))) float f32x4;

// ---------- helpers ----------
__device__ __forceinline__ float softplus_f(float x){
  return (x > 20.0f) ? x : log1pf(expf(x));
}
__device__ __forceinline__ float bflo(unsigned u){ return __uint_as_float(u << 16); }
__device__ __forceinline__ float bfhi(unsigned u){ return __uint_as_float(u & 0xFFFF0000u); }
__device__ __forceinline__ float b2f(ushort_t u){ return __uint_as_float((unsigned)u << 16); }
__device__ __forceinline__ ushort_t f2b(float f){
  unsigned u = __float_as_uint(f);
  unsigned r = u + 0x7FFFu + ((u >> 16) & 1u);
  return (ushort_t)(r >> 16);
}
__device__ __forceinline__ unsigned pack2(float a, float b){
  return (unsigned)f2b(a) | ((unsigned)f2b(b) << 16);
}
__device__ __forceinline__ void unpack16(uint4 a, uint4 b, float* f){
  f[0]=bflo(a.x); f[1]=bfhi(a.x); f[2]=bflo(a.y); f[3]=bfhi(a.y);
  f[4]=bflo(a.z); f[5]=bfhi(a.z); f[6]=bflo(a.w); f[7]=bfhi(a.w);
  f[8]=bflo(b.x); f[9]=bfhi(b.x); f[10]=bflo(b.y); f[11]=bfhi(b.y);
  f[12]=bflo(b.z); f[13]=bfhi(b.z); f[14]=bflo(b.w); f[15]=bfhi(b.w);
}
__device__ __forceinline__ float block_reduce_sum(float v, float* sbuf){
  #pragma unroll
  for (int o = 32; o > 0; o >>= 1) v += __shfl_xor(v, o);
  int t = threadIdx.x, wid = t >> 6, lane = t & 63;
  if (lane == 0) sbuf[wid] = v;
  __syncthreads();
  if (t == 0) sbuf[0] = sbuf[0] + sbuf[1] + sbuf[2] + sbuf[3];
  __syncthreads();
  float r = sbuf[0];
  __syncthreads();
  return r;
}

// ---------- zero fill ----------
__global__ __launch_bounds__(256) void zerok(float4* __restrict__ p, size_t n4){
  float4 z; z.x = z.y = z.z = z.w = 0.f;
  for (size_t i = (size_t)blockIdx.x * 256 + threadIdx.x; i < n4; i += (size_t)gridDim.x * 256)
    p[i] = z;
}

// ---------- layernorm forward -> bf16 G ----------
__global__ __launch_bounds__(256) void ln_fwd(const float* __restrict__ X, const float* __restrict__ gamma,
    const float* __restrict__ beta, ushort_t* __restrict__ Gb, float* __restrict__ mean, float* __restrict__ rstd)
{
  __shared__ float sbuf[8];
  int n = blockIdx.x, t = threadIdx.x;
  size_t idx = (size_t)n * D_ + t;
  float x = X[idx];
  float mu = block_reduce_sum(x, sbuf) * (1.0f / D_);
  float d = x - mu;
  float var = block_reduce_sum(d * d, sbuf) * (1.0f / D_);
  float rs = rsqrtf(var + 1e-5f);
  Gb[idx] = f2b(d * rs * gamma[t] + beta[t]);
  if (t == 0){ mean[n] = mu; rstd[n] = rs; }
}

// ---------- fused weight prep (all 6 outputs, one launch) ----------
// WtQm[65536] | WtF2[131072] | WtF3[262144] | WbQm[65536] | Bt2[131072] | Bt3[262144]
__global__ __launch_bounds__(256) void wprep_all(const float* __restrict__ W_Q2, const float* __restrict__ W_K2,
    const float* __restrict__ W_Q3, const float* __restrict__ W_K3, const float* __restrict__ W_Qm,
    ushort_t* __restrict__ WtQm, ushort_t* __restrict__ WtF2, ushort_t* __restrict__ WtF3,
    ushort_t* __restrict__ WbQm, ushort_t* __restrict__ Bt2, ushort_t* __restrict__ Bt3)
{
  int idx = blockIdx.x * 256 + threadIdx.x;
  if (idx < 65536){
    int m = idx >> 8, k = idx & 255;
    WtQm[idx] = f2b(W_Qm[k * 256 + m]);
    return;
  }
  idx -= 65536;
  if (idx < 131072){
    int m = idx >> 8, k = idx & 255;
    WtF2[idx] = f2b(m < 256 ? W_Q2[k * 256 + m] : W_K2[k * 256 + (m - 256)]);
    return;
  }
  idx -= 131072;
  if (idx < 262144){
    int m = idx >> 8, k = idx & 255;
    WtF3[idx] = f2b(m < 512 ? W_Q3[k * 512 + m] : W_K3[k * 512 + (m - 512)]);
    return;
  }
  idx -= 262144;
  if (idx < 65536){ WbQm[idx] = f2b(W_Qm[idx]); return; }
  idx -= 65536;
  if (idx < 131072){
    int d = idx >> 9, k = idx & 511;
    Bt2[idx] = f2b(k < 256 ? W_Q2[d * 256 + k] : W_K2[d * 256 + (k - 256)]);
    return;
  }
  idx -= 131072;
  if (idx < 262144){
    int d = idx >> 10, k = idx & 1023;
    Bt3[idx] = f2b(k < 512 ? W_Q3[d * 512 + k] : W_K3[d * 512 + (k - 512)]);
  }
}

// ---------- MFMA GEMM: C[N,M] op= A[N,K] @ Bt[M,K]^T ----------
// OUT_MODE: 0 = store fp32, 1 = accumulate fp32, 2 = store bf16
template<int OUT_MODE>
__global__ __launch_bounds__(256) void gemm_bt_mfma(const ushort_t* __restrict__ A,
    const ushort_t* __restrict__ Bt, void* __restrict__ C, int K, int M)
{
  __shared__ __align__(16) ushort_t As[128 * 32];
  __shared__ __align__(16) ushort_t Bs[128 * 32];
  int t = threadIdx.x;
  int wave = t >> 6, lane = t & 63;
  int row0 = blockIdx.y * 128;
  int col0 = blockIdx.x * 128;
  int wrow = (wave & 1) * 64;
  int wcol = (wave >> 1) * 64;
  f32x4 acc[4][4];
  #pragma unroll
  for (int i = 0; i < 4; ++i)
    #pragma unroll
    for (int j = 0; j < 4; ++j)
      acc[i][j] = (f32x4){0.f, 0.f, 0.f, 0.f};
  int srow = t >> 1;
  int soff = (t & 1) * 16;
  const ushort_t* Ag = A + (size_t)(row0 + srow) * K + soff;
  const ushort_t* Bg = Bt + (size_t)(col0 + srow) * K + soff;
  ushort_t* Al = As + srow * 32 + soff;
  ushort_t* Bl = Bs + srow * 32 + soff;
  int lrow = lane & 15, lk = (lane >> 4) * 8;
  for (int k0 = 0; k0 < K; k0 += 32){
    uint4 av0 = *(const uint4*)(Ag + k0);
    uint4 av1 = *(const uint4*)(Ag + k0 + 8);
    uint4 bv0 = *(const uint4*)(Bg + k0);
    uint4 bv1 = *(const uint4*)(Bg + k0 + 8);
    __syncthreads();
    *(uint4*)Al = av0; *(uint4*)(Al + 8) = av1;
    *(uint4*)Bl = bv0; *(uint4*)(Bl + 8) = bv1;
    __syncthreads();
    bf16x8 af[4], bf_[4];
    #pragma unroll
    for (int i = 0; i < 4; ++i)
      af[i] = *(const bf16x8*)(As + (wrow + i * 16 + lrow) * 32 + lk);
    #pragma unroll
    for (int j = 0; j < 4; ++j)
      bf_[j] = *(const bf16x8*)(Bs + (wcol + j * 16 + lrow) * 32 + lk);
    #pragma unroll
    for (int i = 0; i < 4; ++i)
      #pragma unroll
      for (int j = 0; j < 4; ++j)
        acc[i][j] = __builtin_amdgcn_mfma_f32_16x16x32_bf16(af[i], bf_[j], acc[i][j], 0, 0, 0);
  }
  int rbase = row0 + wrow + (lane >> 4) * 4;
  int cbase = col0 + wcol + (lane & 15);
  #pragma unroll
  for (int i = 0; i < 4; ++i){
    #pragma unroll
    for (int r = 0; r < 4; ++r){
      size_t rowoff = (size_t)(rbase + i * 16 + r) * M;
      #pragma unroll
      for (int j = 0; j < 4; ++j){
        int col = cbase + j * 16;
        float v = acc[i][j][r];
        if (OUT_MODE == 0)      ((float*)C)[rowoff + col] = v;
        else if (OUT_MODE == 1) ((float*)C)[rowoff + col] += v;
        else                    ((ushort_t*)C)[rowoff + col] = f2b(v);
      }
    }
  }
}

// ---------- Km = B_mem @ W_Km ----------
__global__ __launch_bounds__(256) void km_kernel(const float* __restrict__ Bm, const float* __restrict__ W,
    float* __restrict__ Km)
{
  __shared__ float sb[D_];
  int k = blockIdx.x, t = threadIdx.x;
  sb[t] = Bm[(size_t)k * D_ + t];
  __syncthreads();
  float acc = 0.f;
  for (int d = 0; d < D_; ++d) acc += sb[d] * W[(size_t)d * D_ + t];
  Km[(size_t)k * D_ + t] = acc;
}

// ---------- CSR build ----------
__global__ __launch_bounds__(256) void hist2(const int* __restrict__ c2, const int* __restrict__ u2,
    int* __restrict__ cnt_c, int* __restrict__ cnt_u, int NE_)
{
  int e = blockIdx.x * 256 + threadIdx.x;
  if (e >= NE_) return;
  atomicAdd(cnt_c + c2[e], 1);
  atomicAdd(cnt_u + u2[e], 1);
}
__global__ __launch_bounds__(256) void hist3(const int* __restrict__ c3, const int* __restrict__ u3,
    const int* __restrict__ v3, int* __restrict__ cnt_c, int* __restrict__ cnt_i, int NT_)
{
  int e = blockIdx.x * 256 + threadIdx.x;
  if (e >= NT_) return;
  atomicAdd(cnt_c + c3[e], 1);
  atomicAdd(cnt_i + u3[e], 1);
  atomicAdd(cnt_i + v3[e], 1);
}
// 4 independent scans, one per block (arrays contiguous at base + b*n)
__global__ __launch_bounds__(256) void scan_excl4(int* __restrict__ basep, int n)
{
  __shared__ int wsum[4];
  __shared__ int carry;
  int* d = basep + blockIdx.x * n;
  int t = threadIdx.x, lane = t & 63, wid = t >> 6;
  if (t == 0) carry = 0;
  __syncthreads();
  for (int base = 0; base < n; base += 256){
    int v = d[base + t];
    int x = v;
    #pragma unroll
    for (int o = 1; o < 64; o <<= 1){
      int y = __shfl_up(x, o);
      if (lane >= o) x += y;
    }
    if (lane == 63) wsum[wid] = x;
    __syncthreads();
    int woff = 0;
    for (int i = 0; i < wid; ++i) woff += wsum[i];
    int excl = carry + woff + x - v;
    d[base + t] = excl;
    __syncthreads();
    if (t == 255) carry = carry + woff + x;
    __syncthreads();
  }
}
__global__ __launch_bounds__(256) void scatter2(const int* __restrict__ c2, const int* __restrict__ u2,
    int* __restrict__ cur_c, int* __restrict__ cur_u, int* __restrict__ adjc_u, uint2* __restrict__ adju2, int NE_)
{
  int e = blockIdx.x * 256 + threadIdx.x;
  if (e >= NE_) return;
  int c = c2[e], u = u2[e];
  int pc = atomicAdd(cur_c + c, 1);
  adjc_u[pc] = u;
  int pu = atomicAdd(cur_u + u, 1);
  uint2 ent; ent.x = (unsigned)c; ent.y = (unsigned)pc;
  adju2[pu] = ent;
}
__global__ __launch_bounds__(256) void scatter3(const int* __restrict__ c3, const int* __restrict__ u3,
    const int* __restrict__ v3, const int* __restrict__ tt, int* __restrict__ cur_c, int* __restrict__ cur_i,
    unsigned* __restrict__ adj3c, uint2* __restrict__ adj3i, int NT_)
{
  int e = blockIdx.x * 256 + threadIdx.x;
  if (e >= NT_) return;
  int c = c3[e], u = u3[e], v = v3[e], tau = tt[e];
  int pc = atomicAdd(cur_c + c, 1);
  adj3c[pc] = (unsigned)u | ((unsigned)v << 15) | ((unsigned)tau << 30);
  int pu = atomicAdd(cur_i + u, 1);
  uint2 eu; eu.x = (unsigned)c | ((unsigned)tau << 15) | ((unsigned)v << 16); eu.y = (unsigned)pc;
  adj3i[pu] = eu;
  int pv = atomicAdd(cur_i + v, 1);
  uint2 ev; ev.x = (unsigned)c | ((unsigned)tau << 15) | ((unsigned)u << 16); ev.y = (unsigned)pc;
  adj3i[pv] = ev;
}

// ---------- order-2 by-c: 16 lanes/edge, 4 edges concurrent, online softmax + dQ2 ----------
__global__ __launch_bounds__(256) void e2_rowc(const ushort_t* __restrict__ QK2, const int* __restrict__ cur_c,
    const int* __restrict__ adjc_u, ushort_t* __restrict__ dstage, float* __restrict__ s2c,
    float2* __restrict__ ml2, float* __restrict__ accum, const float* __restrict__ b2p,
    const float* __restrict__ l2p)
{
  __shared__ float sbuf[4];
  int wave = threadIdx.x >> 6, lane = threadIdx.x & 63;
  int r = blockIdx.x * 4 + wave;
  int quarter = lane >> 4, sub = lane & 15;
  float b2s = fminf(softplus_f(*b2p), 5.0f) * 0.0625f;
  float lam2 = softplus_f(*l2p);
  int start = (r > 0) ? cur_c[r - 1] : 0;
  int end = cur_c[r];
  const ushort_t* qrow = QK2 + (size_t)r * 512 + sub * 16;
  float qf[16];
  unpack16(*(const uint4*)qrow, *(const uint4*)(qrow + 8), qf);
  float m = -1e30f, l = 0.f;
  float a[16] = {};
  for (int p = start + quarter; p < end; p += 4){
    int u = adjc_u[p];
    const ushort_t* krow = QK2 + (size_t)u * 512 + 256 + sub * 16;
    float kf[16];
    unpack16(*(const uint4*)krow, *(const uint4*)(krow + 8), kf);
    float d = 0.f;
    #pragma unroll
    for (int j = 0; j < 16; ++j) d += qf[j] * kf[j];
    d += __shfl_xor(d, 1); d += __shfl_xor(d, 2); d += __shfl_xor(d, 4); d += __shfl_xor(d, 8);
    float s = d * b2s;
    if (sub == 0) s2c[p] = s;
    float mn = fmaxf(m, s);
    float sc = expf(m - mn);
    float pt = expf(s - mn);
    l = l * sc + pt;
    #pragma unroll
    for (int j = 0; j < 16; ++j) a[j] = a[j] * sc + pt * kf[j];
    m = mn;
  }
  // cross-quarter merge
  float M = fmaxf(m, __shfl_xor(m, 16)); M = fmaxf(M, __shfl_xor(M, 32));
  float scq = expf(m - M);
  float L = l * scq;
  L += __shfl_xor(L, 16); L += __shfl_xor(L, 32);
  #pragma unroll
  for (int j = 0; j < 16; ++j){
    float x = a[j] * scq;
    x += __shfl_xor(x, 16); x += __shfl_xor(x, 32);
    a[j] = x;
  }
  float lse = 0.f, linv = 0.f, coef = 0.f;
  if (end > start){ lse = M + logf(L); linv = 1.0f / L; coef = -lam2 * 0.0625f * linv; }
  if (lane == 0){
    float2 ml; ml.x = M; ml.y = linv;
    ml2[r] = ml;
    sbuf[wave] = lse;
  }
  if (quarter == 0){
    ushort_t* dst = dstage + (size_t)r * 512 + sub * 16;
    uint4 p0, p1;
    p0.x = pack2(coef*a[0], coef*a[1]);   p0.y = pack2(coef*a[2], coef*a[3]);
    p0.z = pack2(coef*a[4], coef*a[5]);   p0.w = pack2(coef*a[6], coef*a[7]);
    p1.x = pack2(coef*a[8], coef*a[9]);   p1.y = pack2(coef*a[10], coef*a[11]);
    p1.z = pack2(coef*a[12], coef*a[13]); p1.w = pack2(coef*a[14], coef*a[15]);
    *(uint4*)dst = p0; *(uint4*)(dst + 8) = p1;
  }
  __syncthreads();
  if (threadIdx.x == 0) atomicAdd(accum, sbuf[0] + sbuf[1] + sbuf[2] + sbuf[3]);
}

// ---------- order-2 by-u: 16 lanes/edge, stored scores, dK2 ----------
__global__ __launch_bounds__(256) void e2_rowu(const ushort_t* __restrict__ QK2, const int* __restrict__ cur_u,
    const uint2* __restrict__ adju2, const float* __restrict__ s2c, const float2* __restrict__ ml2,
    ushort_t* __restrict__ dstage, const float* __restrict__ l2p)
{
  int wave = threadIdx.x >> 6, lane = threadIdx.x & 63;
  int r = blockIdx.x * 4 + wave;
  int quarter = lane >> 4, sub = lane & 15;
  float lam2 = softplus_f(*l2p);
  int start = (r > 0) ? cur_u[r - 1] : 0;
  int end = cur_u[r];
  float a[16] = {};
  for (int p = start + quarter; p < end; p += 4){
    uint2 ent = adju2[p];
    int c = (int)ent.x;
    float2 ml = ml2[c];
    float pe = expf(s2c[ent.y] - ml.x) * ml.y;
    const ushort_t* qrow = QK2 + (size_t)c * 512 + sub * 16;
    float qf[16];
    unpack16(*(const uint4*)qrow, *(const uint4*)(qrow + 8), qf);
    #pragma unroll
    for (int j = 0; j < 16; ++j) a[j] += pe * qf[j];
  }
  #pragma unroll
  for (int j = 0; j < 16; ++j){
    float x = a[j];
    x += __shfl_xor(x, 16); x += __shfl_xor(x, 32);
    a[j] = x;
  }
  float coef = -lam2 * 0.0625f;
  if (quarter == 0){
    ushort_t* dst = dstage + (size_t)r * 512 + 256 + sub * 16;
    uint4 p0, p1;
    p0.x = pack2(coef*a[0], coef*a[1]);   p0.y = pack2(coef*a[2], coef*a[3]);
    p0.z = pack2(coef*a[4], coef*a[5]);   p0.w = pack2(coef*a[6], coef*a[7]);
    p1.x = pack2(coef*a[8], coef*a[9]);   p1.y = pack2(coef*a[10], coef*a[11]);
    p1.z = pack2(coef*a[12], coef*a[13]); p1.w = pack2(coef*a[14], coef*a[15]);
    *(uint4*)dst = p0; *(uint4*)(dst + 8) = p1;
  }
}

// ---------- order-3 by-c: online softmax + dQ3, wave per row (8 elems/lane) ----------
__global__ __launch_bounds__(256) void e3_rowc(const ushort_t* __restrict__ QK3, const float* __restrict__ Tt,
    const int* __restrict__ cur_c, const unsigned* __restrict__ adj3c, ushort_t* __restrict__ dstage,
    float* __restrict__ s3c, float2* __restrict__ ml3, float* __restrict__ accum,
    const float* __restrict__ b3p, const float* __restrict__ l3p)
{
  __shared__ float sbuf[4];
  int wave = threadIdx.x >> 6, lane = threadIdx.x & 63;
  int r = blockIdx.x * 4 + wave;
  float b3s = fminf(softplus_f(*b3p), 5.0f) * 0.0625f;
  float lam3 = softplus_f(*l3p);
  int start = (r > 0) ? cur_c[r - 1] : 0;
  int end = cur_c[r];
  uint4 qw = *(const uint4*)(QK3 + (size_t)r * 1024 + lane * 8);
  float q[8] = {bflo(qw.x),bfhi(qw.x),bflo(qw.y),bfhi(qw.y),bflo(qw.z),bfhi(qw.z),bflo(qw.w),bfhi(qw.w)};
  float4 t0a = ((const float4*)Tt)[2*lane], t0b = ((const float4*)Tt)[2*lane+1];
  float4 t1a = ((const float4*)(Tt + 512))[2*lane], t1b = ((const float4*)(Tt + 512))[2*lane+1];
  float T0[8] = {t0a.x,t0a.y,t0a.z,t0a.w,t0b.x,t0b.y,t0b.z,t0b.w};
  float T1[8] = {t1a.x,t1a.y,t1a.z,t1a.w,t1b.x,t1b.y,t1b.z,t1b.w};
  float m = -1e30f, l = 0.f;
  float a[8] = {};
  for (int p = start; p < end; ++p){
    unsigned ent = adj3c[p];
    int u = ent & 32767, v = (ent >> 15) & 32767, tau = (ent >> 30) & 1;
    uint4 bw = *(const uint4*)(QK3 + (size_t)u * 1024 + 512 + lane * 8);
    uint4 cw = *(const uint4*)(QK3 + (size_t)v * 1024 + 512 + lane * 8);
    float kb[8] = {bflo(bw.x),bfhi(bw.x),bflo(bw.y),bfhi(bw.y),bflo(bw.z),bfhi(bw.z),bflo(bw.w),bfhi(bw.w)};
    float kc[8] = {bflo(cw.x),bfhi(cw.x),bflo(cw.y),bfhi(cw.y),bflo(cw.z),bfhi(cw.z),bflo(cw.w),bfhi(cw.w)};
    float prod[8];
    float d = 0.f;
    #pragma unroll
    for (int j = 0; j < 8; ++j){
      float tj = tau ? T1[j] : T0[j];
      prod[j] = kb[j] * kc[j] * tj;
      d += q[j] * prod[j];
    }
    #pragma unroll
    for (int o = 32; o > 0; o >>= 1) d += __shfl_xor(d, o);
    float s = d * b3s;
    if (lane == 0) s3c[p] = s;
    float mn = fmaxf(m, s);
    float sc = expf(m - mn);
    float pt = expf(s - mn);
    l = l * sc + pt;
    #pragma unroll
    for (int j = 0; j < 8; ++j) a[j] = a[j]*sc + pt*prod[j];
    m = mn;
  }
  float lse = 0.f, linv = 0.f, coef = 0.f;
  if (end > start){ lse = m + logf(l); linv = 1.0f / l; coef = -lam3 * 0.0625f * linv; }
  uint4 o4;
  o4.x = pack2(coef*a[0], coef*a[1]); o4.y = pack2(coef*a[2], coef*a[3]);
  o4.z = pack2(coef*a[4], coef*a[5]); o4.w = pack2(coef*a[6], coef*a[7]);
  *(uint4*)(dstage + (size_t)r * 1024 + lane * 8) = o4;
  if (lane == 0){
    float2 ml; ml.x = m; ml.y = linv;
    ml3[r] = ml;
    sbuf[wave] = lse;
  }
  __syncthreads();
  if (threadIdx.x == 0) atomicAdd(accum, sbuf[0] + sbuf[1] + sbuf[2] + sbuf[3]);
}

// ---------- order-3 incidence: stored scores, dK3, wave per row ----------
__global__ __launch_bounds__(256) void e3_rowi(const ushort_t* __restrict__ QK3, const float* __restrict__ Tt,
    const int* __restrict__ cur_i, const uint2* __restrict__ adj3i, const float* __restrict__ s3c,
    const float2* __restrict__ ml3, ushort_t* __restrict__ dstage, const float* __restrict__ l3p)
{
  int wave = threadIdx.x >> 6, lane = threadIdx.x & 63;
  int r = blockIdx.x * 4 + wave;
  float lam3 = softplus_f(*l3p);
  int start = (r > 0) ? cur_i[r - 1] : 0;
  int end = cur_i[r];
  float4 t0a = ((const float4*)Tt)[2*lane], t0b = ((const float4*)Tt)[2*lane+1];
  float4 t1a = ((const float4*)(Tt + 512))[2*lane], t1b = ((const float4*)(Tt + 512))[2*lane+1];
  float T0[8] = {t0a.x,t0a.y,t0a.z,t0a.w,t0b.x,t0b.y,t0b.z,t0b.w};
  float T1[8] = {t1a.x,t1a.y,t1a.z,t1a.w,t1b.x,t1b.y,t1b.z,t1b.w};
  float a[8] = {};
  for (int p = start; p < end; ++p){
    uint2 ent = adj3i[p];
    int c = ent.x & 32767, tau = (ent.x >> 15) & 1, other = (ent.x >> 16) & 32767;
    float2 ml = ml3[c];
    float pe = expf(s3c[ent.y] - ml.x) * ml.y;
    uint4 qw = *(const uint4*)(QK3 + (size_t)c * 1024 + lane * 8);
    uint4 ow = *(const uint4*)(QK3 + (size_t)other * 1024 + 512 + lane * 8);
    float q[8] = {bflo(qw.x),bfhi(qw.x),bflo(qw.y),bfhi(qw.y),bflo(qw.z),bfhi(qw.z),bflo(qw.w),bfhi(qw.w)};
    float ko[8] = {bflo(ow.x),bfhi(ow.x),bflo(ow.y),bfhi(ow.y),bflo(ow.z),bfhi(ow.z),bflo(ow.w),bfhi(ow.w)};
    #pragma unroll
    for (int j = 0; j < 8; ++j){
      float tj = tau ? T1[j] : T0[j];
      a[j] += pe * q[j] * ko[j] * tj;
    }
  }
  float coef = -lam3 * 0.0625f;
  uint4 o4;
  o4.x = pack2(coef*a[0], coef*a[1]); o4.y = pack2(coef*a[2], coef*a[3]);
  o4.z = pack2(coef*a[4], coef*a[5]); o4.w = pack2(coef*a[6], coef*a[7]);
  *(uint4*)(dstage + (size_t)r * 1024 + 512 + lane * 8) = o4;
}

// ---------- memory term: bf16 in/out, fused lse reduce ----------
__global__ __launch_bounds__(256) void mem_rows(const ushort_t* __restrict__ Qmf, const float* __restrict__ Km,
    ushort_t* __restrict__ dQmb, float* __restrict__ accum, const float* __restrict__ bmp,
    const float* __restrict__ lmp)
{
  __shared__ float sKm[KSLOT * 264];
  __shared__ float sq[D_];
  __shared__ float sS[KSLOT];
  int n = blockIdx.x, t = threadIdx.x;
  for (int idx = t; idx < KSLOT * D_; idx += 256){
    int k = idx >> 8, d = idx & 255;
    sKm[k * 264 + d] = Km[idx];
  }
  sq[t] = b2f(Qmf[(size_t)n * D_ + t]);
  __syncthreads();
  float bm = fminf(softplus_f(*bmp), 5.0f);
  int g = t >> 3, i = t & 7;
  float part = 0.f;
  #pragma unroll
  for (int s = 0; s < 32; ++s){
    int d = i + (s << 3);
    part += sq[d] * sKm[g * 264 + d];
  }
  part += __shfl_xor(part, 1); part += __shfl_xor(part, 2); part += __shfl_xor(part, 4);
  if (i == 0) sS[g] = part * bm * 0.0625f;
  __syncthreads();
  if (t < 32){
    float v = sS[t];
    float m = v;
    #pragma unroll
    for (int o = 16; o > 0; o >>= 1) m = fmaxf(m, __shfl_xor(m, o));
    float e = expf(v - m);
    float se = e;
    #pragma unroll
    for (int o = 16; o > 0; o >>= 1) se += __shfl_xor(se, o);
    sS[t] = e / se;
    if (t == 0) atomicAdd(accum, m + logf(se));
  }
  __syncthreads();
  float acc = 0.f;
  #pragma unroll 8
  for (int k = 0; k < KSLOT; ++k) acc += sS[k] * sKm[k * 264 + t];
  float lam = softplus_f(*lmp);
  dQmb[(size_t)n * D_ + t] = f2b(-lam * 0.0625f * acc);
}

// ---------- LN backward + clips + update ----------
__global__ __launch_bounds__(256) void ln_bwd_update(const float* __restrict__ X, const float* __restrict__ dG,
    const float* __restrict__ gamma, const float* __restrict__ mean, const float* __restrict__ rstd,
    const float* __restrict__ step_p, float* __restrict__ out)
{
  __shared__ float sbuf[8];
  int n = blockIdx.x, t = threadIdx.x;
  size_t idx = (size_t)n * D_ + t;
  float x = X[idx];
  float rs = rstd[n];
  float xh = (x - mean[n]) * rs;
  float dxh = dG[idx] * gamma[t];
  float s1 = block_reduce_sum(dxh, sbuf) * (1.0f / D_);
  float s2v = block_reduce_sum(dxh * xh, sbuf) * (1.0f / D_);
  float dx = rs * (dxh - s1 - xh * s2v);
  float gn2 = block_reduce_sum(dx * dx, sbuf);
  float gn = fmaxf(sqrtf(gn2), 1e-6f);
  float gsc = fminf(1.0f / gn, 1.0f);
  float stp = step_p[0] * 0.9999f;
  float xn = x - stp * gsc * dx;
  float sn2 = block_reduce_sum(xn * xn, sbuf);
  float sn = fmaxf(sqrtf(sn2), 1e-6f);
  float ssc = fminf(10.0f / sn, 1.0f);
  out[idx] = xn * ssc;
}

// ---------- final energy scalar ----------
__global__ void efinal(const float* __restrict__ accum, const float* l2p, const float* l3p, const float* lmp,
    const float* b2p, const float* b3p, const float* bmp, float* __restrict__ outE)
{
  float l2 = softplus_f(*l2p), l3 = softplus_f(*l3p), lm = softplus_f(*lmp);
  float b2 = fminf(softplus_f(*b2p), 5.0f);
  float b3 = fminf(softplus_f(*b3p), 5.0f);
  float bm = fminf(softplus_f(*bmp), 5.0f);
  *outE = -(l2 / b2) * accum[0] - (l3 / b3) * accum[1] - (lm / bm) * accum[2];
}

static inline void zfill(void* p, size_t nElems, hipStream_t stream){
  size_t n4 = nElems / 4;
  int blocks = (int)(((n4 + 255) / 256) < 16384 ? ((n4 + 255) / 256) : 16384);
  if (blocks < 1) blocks = 1;
  zerok<<<blocks, 256, 0, stream>>>((float4*)p, n4);
}

extern "C" void kernel_launch(void* const* d_in, const int* in_sizes, int n_in,
                              void* d_out, int out_size, void* d_ws, size_t ws_size,
                              hipStream_t stream)
{
  const float* X     = (const float*)d_in[0];
  const int*   c2    = (const int*)d_in[1];
  const int*   u2    = (const int*)d_in[2];
  const int*   c3    = (const int*)d_in[3];
  const int*   u3    = (const int*)d_in[4];
  const int*   v3    = (const int*)d_in[5];
  const int*   tt    = (const int*)d_in[6];
  const float* stepp = (const float*)d_in[7];
  const float* gamma = (const float*)d_in[8];
  const float* beta  = (const float*)d_in[9];
  const float* W_Q2  = (const float*)d_in[10];
  const float* W_K2  = (const float*)d_in[11];
  const float* W_Q3  = (const float*)d_in[12];
  const float* W_K3  = (const float*)d_in[13];
  const float* T_tau = (const float*)d_in[14];
  const float* W_Qm  = (const float*)d_in[15];
  const float* W_Km  = (const float*)d_in[16];
  const float* B_mem = (const float*)d_in[17];
  const float* l2p   = (const float*)d_in[18];
  const float* l3p   = (const float*)d_in[19];
  const float* lmp   = (const float*)d_in[20];
  const float* b2p   = (const float*)d_in[21];
  const float* b3p   = (const float*)d_in[22];
  const float* bmp   = (const float*)d_in[23];

  const int N  = in_sizes[0] / D_;
  const int NE = in_sizes[1];
  const int NT = in_sizes[3];
  const size_t ND = (size_t)N * D_;

  // ---- byte arena (~165 MB) ----
  char* base = (char*)d_ws;
  size_t off = 0;
  auto alloc = [&](size_t bytes) -> void* {
    void* p = base + off;
    off += (bytes + 255) & ~(size_t)255;
    return p;
  };
  ushort_t* Gb    = (ushort_t*)alloc(ND * 2);            // 16 MB
  ushort_t* bufA  = (ushort_t*)alloc(ND * 4 * 2);        // 64 MB: fwd QK per phase
  ushort_t* bufB  = (ushort_t*)alloc(ND * 4 * 2);        // 64 MB: grad staging per phase
  int*      curs  = (int*)     alloc((size_t)N * 4 * 4); // curc2|curu2|curc3|curi3 contiguous
  int*      adjc_u= (int*)     alloc((size_t)NE * 4);
  uint2*    adju2 = (uint2*)   alloc((size_t)NE * 8);
  unsigned* adj3c = (unsigned*)alloc((size_t)NT * 4);
  uint2*    adj3i = (uint2*)   alloc((size_t)NT * 2 * 8);
  float*    s2c   = (float*)   alloc((size_t)NE * 4);
  float*    s3c   = (float*)   alloc((size_t)NT * 4);
  float2*   ml2   = (float2*)  alloc((size_t)N * 8);
  float2*   ml3   = (float2*)  alloc((size_t)N * 8);
  float*    Km    = (float*)   alloc((size_t)KSLOT * D_ * 4);
  float*    meanb = (float*)   alloc((size_t)N * 4);
  float*    rstdb = (float*)   alloc((size_t)N * 4);
  float*    accum = (float*)   alloc(64);
  ushort_t* WtQm  = (ushort_t*)alloc(65536 * 2);
  ushort_t* WtF2  = (ushort_t*)alloc(131072 * 2);
  ushort_t* WtF3  = (ushort_t*)alloc(262144 * 2);
  ushort_t* WbQm  = (ushort_t*)alloc(65536 * 2);
  ushort_t* Bt2   = (ushort_t*)alloc(131072 * 2);
  ushort_t* Bt3   = (ushort_t*)alloc(262144 * 2);

  int* curc2 = curs;
  int* curu2 = curs + N;
  int* curc3 = curs + 2 * N;
  int* curi3 = curs + 3 * N;
  float* out = (float*)d_out;

  zfill(curs, (size_t)N * 4, stream);
  zfill(accum, 16, stream);

  // 1. LN forward + weight prep
  ln_fwd<<<N, 256, 0, stream>>>(X, gamma, beta, Gb, meanb, rstdb);
  wprep_all<<<(917504 + 255) / 256, 256, 0, stream>>>(W_Q2, W_K2, W_Q3, W_K3, W_Qm,
      WtQm, WtF2, WtF3, WbQm, Bt2, Bt3);

  // CSR build
  hist2<<<(NE + 255) / 256, 256, 0, stream>>>(c2, u2, curc2, curu2, NE);
  hist3<<<(NT + 255) / 256, 256, 0, stream>>>(c3, u3, v3, curc3, curi3, NT);
  scan_excl4<<<4, 256, 0, stream>>>(curs, N);
  scatter2<<<(NE + 255) / 256, 256, 0, stream>>>(c2, u2, curc2, curu2, adjc_u, adju2, NE);
  scatter3<<<(NT + 255) / 256, 256, 0, stream>>>(c3, u3, v3, tt, curc3, curi3, adj3c, adj3i, NT);

  dim3 g256(2, N / 128), g512(4, N / 128), g1024(8, N / 128);

  // 2. memory phase
  gemm_bt_mfma<2><<<g256, 256, 0, stream>>>(Gb, WtQm, bufA, D_, D_);          // Qm fwd (bf16)
  km_kernel<<<KSLOT, 256, 0, stream>>>(B_mem, W_Km, Km);
  mem_rows<<<N, 256, 0, stream>>>(bufA, Km, bufB, accum + 2, bmp, lmp);        // dQm -> bufB
  gemm_bt_mfma<0><<<g256, 256, 0, stream>>>(bufB, WbQm, out, D_, D_);          // dG = dQm WQm^T

  // 3. order-2 phase
  gemm_bt_mfma<2><<<g512, 256, 0, stream>>>(Gb, WtF2, bufA, D_, 512);          // [Q2|K2]
  e2_rowc<<<N / 4, 256, 0, stream>>>(bufA, curc2, adjc_u, bufB, s2c, ml2, accum + 0, b2p, l2p);
  e2_rowu<<<N / 4, 256, 0, stream>>>(bufA, curu2, adju2, s2c, ml2, bufB, l2p);
  gemm_bt_mfma<1><<<g256, 256, 0, stream>>>(bufB, Bt2, out, 512, D_);          // dG += [dQ2|dK2] Bt2^T

  // 4. order-3 phase
  gemm_bt_mfma<2><<<g1024, 256, 0, stream>>>(Gb, WtF3, bufA, D_, 1024);        // [Q3|K3]
  e3_rowc<<<N / 4, 256, 0, stream>>>(bufA, T_tau, curc3, adj3c, bufB, s3c, ml3, accum + 1, b3p, l3p);
  e3_rowi<<<N / 4, 256, 0, stream>>>(bufA, T_tau, curi3, adj3i, s3c, ml3, bufB, l3p);
  gemm_bt_mfma<1><<<g256, 256, 0, stream>>>(bufB, Bt3, out, 1024, D_);         // dG += [dQ3|dK3] Bt3^T

  // 5. LN backward + clips + update
  ln_bwd_update<<<N, 256, 0, stream>>>(X, out, gamma, meanb, rstdb, stepp, out);

  // 6. energy scalar
  efinal<<<1, 1, 0, stream>>>(accum, l2p, l3p, lmp, b2p, b3p, bmp, out + ND);
}

// Round 6
// 1015.630 us; speedup vs baseline: 10.6835x; 1.4954x over previous
//
#include <hip/hip_runtime.h>
#include <math.h>

#define D_ 256
#define KSLOT 32
typedef unsigned short ushort_t;
typedef __attribute__((ext_vector_type(8))) short bf16x8;
typedef __attribute__((ext_vector_type(4))) float f32x4;

// ---------- helpers ----------
__device__ __forceinline__ float softplus_f(float x){
  return (x > 20.0f) ? x : log1pf(expf(x));
}
__device__ __forceinline__ float bflo(unsigned u){ return __uint_as_float(u << 16); }
__device__ __forceinline__ float bfhi(unsigned u){ return __uint_as_float(u & 0xFFFF0000u); }
__device__ __forceinline__ ushort_t f2b(float f){
  unsigned u = __float_as_uint(f);
  unsigned r = u + 0x7FFFu + ((u >> 16) & 1u);
  return (ushort_t)(r >> 16);
}
__device__ __forceinline__ unsigned pack2(float a, float b){
  return (unsigned)f2b(a) | ((unsigned)f2b(b) << 16);
}
__device__ __forceinline__ void unpack16(uint4 a, uint4 b, float* f){
  f[0]=bflo(a.x); f[1]=bfhi(a.x); f[2]=bflo(a.y); f[3]=bfhi(a.y);
  f[4]=bflo(a.z); f[5]=bfhi(a.z); f[6]=bflo(a.w); f[7]=bfhi(a.w);
  f[8]=bflo(b.x); f[9]=bfhi(b.x); f[10]=bflo(b.y); f[11]=bfhi(b.y);
  f[12]=bflo(b.z); f[13]=bfhi(b.z); f[14]=bflo(b.w); f[15]=bfhi(b.w);
}
__device__ __forceinline__ float block_reduce_sum(float v, float* sbuf){
  #pragma unroll
  for (int o = 32; o > 0; o >>= 1) v += __shfl_xor(v, o);
  int t = threadIdx.x, wid = t >> 6, lane = t & 63;
  if (lane == 0) sbuf[wid] = v;
  __syncthreads();
  if (t == 0) sbuf[0] = sbuf[0] + sbuf[1] + sbuf[2] + sbuf[3];
  __syncthreads();
  float r = sbuf[0];
  __syncthreads();
  return r;
}

// ---------- zero fill ----------
__global__ __launch_bounds__(256) void zerok(float4* __restrict__ p, size_t n4){
  float4 z; z.x = z.y = z.z = z.w = 0.f;
  for (size_t i = (size_t)blockIdx.x * 256 + threadIdx.x; i < n4; i += (size_t)gridDim.x * 256)
    p[i] = z;
}

// ---------- layernorm forward -> bf16 G ----------
__global__ __launch_bounds__(256) void ln_fwd(const float* __restrict__ X, const float* __restrict__ gamma,
    const float* __restrict__ beta, ushort_t* __restrict__ Gb, float* __restrict__ mean, float* __restrict__ rstd)
{
  __shared__ float sbuf[8];
  int n = blockIdx.x, t = threadIdx.x;
  size_t idx = (size_t)n * D_ + t;
  float x = X[idx];
  float mu = block_reduce_sum(x, sbuf) * (1.0f / D_);
  float d = x - mu;
  float var = block_reduce_sum(d * d, sbuf) * (1.0f / D_);
  float rs = rsqrtf(var + 1e-5f);
  Gb[idx] = f2b(d * rs * gamma[t] + beta[t]);
  if (t == 0){ mean[n] = mu; rstd[n] = rs; }
}

// ---------- fused weight prep ----------
// WtQm[65536] | WtF2[131072] | WtF3[262144] | WbQm[65536] | Bt2[131072] | Bt3[262144]
__global__ __launch_bounds__(256) void wprep_all(const float* __restrict__ W_Q2, const float* __restrict__ W_K2,
    const float* __restrict__ W_Q3, const float* __restrict__ W_K3, const float* __restrict__ W_Qm,
    ushort_t* __restrict__ WtQm, ushort_t* __restrict__ WtF2, ushort_t* __restrict__ WtF3,
    ushort_t* __restrict__ WbQm, ushort_t* __restrict__ Bt2, ushort_t* __restrict__ Bt3)
{
  int idx = blockIdx.x * 256 + threadIdx.x;
  if (idx < 65536){
    int m = idx >> 8, k = idx & 255;
    WtQm[idx] = f2b(W_Qm[k * 256 + m]);
    return;
  }
  idx -= 65536;
  if (idx < 131072){
    int m = idx >> 8, k = idx & 255;
    WtF2[idx] = f2b(m < 256 ? W_Q2[k * 256 + m] : W_K2[k * 256 + (m - 256)]);
    return;
  }
  idx -= 131072;
  if (idx < 262144){
    int m = idx >> 8, k = idx & 255;
    WtF3[idx] = f2b(m < 512 ? W_Q3[k * 512 + m] : W_K3[k * 512 + (m - 512)]);
    return;
  }
  idx -= 262144;
  if (idx < 65536){ WbQm[idx] = f2b(W_Qm[idx]); return; }
  idx -= 65536;
  if (idx < 131072){
    int d = idx >> 9, k = idx & 511;
    Bt2[idx] = f2b(k < 256 ? W_Q2[d * 256 + k] : W_K2[d * 256 + (k - 256)]);
    return;
  }
  idx -= 131072;
  if (idx < 262144){
    int d = idx >> 10, k = idx & 1023;
    Bt3[idx] = f2b(k < 512 ? W_Q3[d * 512 + k] : W_K3[d * 512 + (k - 512)]);
  }
}

// ---------- MFMA GEMM: C[N,M] op= A[N,K] @ Bt[M,K]^T ----------
// OUT_MODE: 0 = store fp32, 1 = accumulate fp32, 2 = store bf16
template<int OUT_MODE>
__global__ __launch_bounds__(256) void gemm_bt_mfma(const ushort_t* __restrict__ A,
    const ushort_t* __restrict__ Bt, void* __restrict__ C, int K, int M)
{
  __shared__ __align__(16) ushort_t As[128 * 32];
  __shared__ __align__(16) ushort_t Bs[128 * 32];
  int t = threadIdx.x;
  int wave = t >> 6, lane = t & 63;
  int row0 = blockIdx.y * 128;
  int col0 = blockIdx.x * 128;
  int wrow = (wave & 1) * 64;
  int wcol = (wave >> 1) * 64;
  f32x4 acc[4][4];
  #pragma unroll
  for (int i = 0; i < 4; ++i)
    #pragma unroll
    for (int j = 0; j < 4; ++j)
      acc[i][j] = (f32x4){0.f, 0.f, 0.f, 0.f};
  int srow = t >> 1;
  int soff = (t & 1) * 16;
  const ushort_t* Ag = A + (size_t)(row0 + srow) * K + soff;
  const ushort_t* Bg = Bt + (size_t)(col0 + srow) * K + soff;
  ushort_t* Al = As + srow * 32 + soff;
  ushort_t* Bl = Bs + srow * 32 + soff;
  int lrow = lane & 15, lk = (lane >> 4) * 8;
  for (int k0 = 0; k0 < K; k0 += 32){
    uint4 av0 = *(const uint4*)(Ag + k0);
    uint4 av1 = *(const uint4*)(Ag + k0 + 8);
    uint4 bv0 = *(const uint4*)(Bg + k0);
    uint4 bv1 = *(const uint4*)(Bg + k0 + 8);
    __syncthreads();
    *(uint4*)Al = av0; *(uint4*)(Al + 8) = av1;
    *(uint4*)Bl = bv0; *(uint4*)(Bl + 8) = bv1;
    __syncthreads();
    bf16x8 af[4], bf_[4];
    #pragma unroll
    for (int i = 0; i < 4; ++i)
      af[i] = *(const bf16x8*)(As + (wrow + i * 16 + lrow) * 32 + lk);
    #pragma unroll
    for (int j = 0; j < 4; ++j)
      bf_[j] = *(const bf16x8*)(Bs + (wcol + j * 16 + lrow) * 32 + lk);
    #pragma unroll
    for (int i = 0; i < 4; ++i)
      #pragma unroll
      for (int j = 0; j < 4; ++j)
        acc[i][j] = __builtin_amdgcn_mfma_f32_16x16x32_bf16(af[i], bf_[j], acc[i][j], 0, 0, 0);
  }
  int rbase = row0 + wrow + (lane >> 4) * 4;
  int cbase = col0 + wcol + (lane & 15);
  #pragma unroll
  for (int i = 0; i < 4; ++i){
    #pragma unroll
    for (int r = 0; r < 4; ++r){
      size_t rowoff = (size_t)(rbase + i * 16 + r) * M;
      #pragma unroll
      for (int j = 0; j < 4; ++j){
        int col = cbase + j * 16;
        float v = acc[i][j][r];
        if (OUT_MODE == 0)      ((float*)C)[rowoff + col] = v;
        else if (OUT_MODE == 1) ((float*)C)[rowoff + col] += v;
        else                    ((ushort_t*)C)[rowoff + col] = f2b(v);
      }
    }
  }
}

// ---------- Km = B_mem @ W_Km -> bf16 into padded [128,256] buffer ----------
__global__ __launch_bounds__(256) void km_kernel(const float* __restrict__ Bm, const float* __restrict__ W,
    ushort_t* __restrict__ Kmb)
{
  __shared__ float sb[D_];
  int k = blockIdx.x, t = threadIdx.x;
  sb[t] = Bm[(size_t)k * D_ + t];
  __syncthreads();
  float acc = 0.f;
  for (int d = 0; d < D_; ++d) acc += sb[d] * W[(size_t)d * D_ + t];
  Kmb[(size_t)k * D_ + t] = f2b(acc);
}

// ---------- mem softmax: Sm[N,128] fp32 (cols 0..31 valid) -> P' bf16 [N,128] + lse ----------
__global__ __launch_bounds__(256) void softmax32(const float* __restrict__ Sm, ushort_t* __restrict__ Pb,
    float* __restrict__ lseM, const float* __restrict__ bmp, const float* __restrict__ lmp)
{
  int t = threadIdx.x;
  int r = blockIdx.x * 8 + (t >> 5);
  int lane = t & 31;
  float bs = fminf(softplus_f(*bmp), 5.0f) * 0.0625f;
  float coef = -softplus_f(*lmp) * 0.0625f;
  float s = Sm[(size_t)r * 128 + lane] * bs;
  float m = s;
  #pragma unroll
  for (int o = 16; o > 0; o >>= 1) m = fmaxf(m, __shfl_xor(m, o, 32));
  float e = expf(s - m);
  float se = e;
  #pragma unroll
  for (int o = 16; o > 0; o >>= 1) se += __shfl_xor(se, o, 32);
  ushort_t* dst = Pb + (size_t)r * 128 + lane;
  dst[0] = f2b(coef * e / se);
  dst[32] = 0; dst[64] = 0; dst[96] = 0;
  if (lane == 0) lseM[r] = m + logf(se);
}

// ---------- CSR build ----------
__global__ __launch_bounds__(256) void hist2(const int* __restrict__ c2, const int* __restrict__ u2,
    int* __restrict__ cnt_c, int* __restrict__ cnt_u, int NE_)
{
  int e = blockIdx.x * 256 + threadIdx.x;
  if (e >= NE_) return;
  atomicAdd(cnt_c + c2[e], 1);
  atomicAdd(cnt_u + u2[e], 1);
}
__global__ __launch_bounds__(256) void hist3(const int* __restrict__ c3, const int* __restrict__ u3,
    const int* __restrict__ v3, int* __restrict__ cnt_c, int* __restrict__ cnt_i, int NT_)
{
  int e = blockIdx.x * 256 + threadIdx.x;
  if (e >= NT_) return;
  atomicAdd(cnt_c + c3[e], 1);
  atomicAdd(cnt_i + u3[e], 1);
  atomicAdd(cnt_i + v3[e], 1);
}
__global__ __launch_bounds__(256) void scan_excl4(int* __restrict__ basep, int n)
{
  __shared__ int wsum[4];
  __shared__ int carry;
  int* d = basep + blockIdx.x * n;
  int t = threadIdx.x, lane = t & 63, wid = t >> 6;
  if (t == 0) carry = 0;
  __syncthreads();
  for (int base = 0; base < n; base += 256){
    int v = d[base + t];
    int x = v;
    #pragma unroll
    for (int o = 1; o < 64; o <<= 1){
      int y = __shfl_up(x, o);
      if (lane >= o) x += y;
    }
    if (lane == 63) wsum[wid] = x;
    __syncthreads();
    int woff = 0;
    for (int i = 0; i < wid; ++i) woff += wsum[i];
    int excl = carry + woff + x - v;
    d[base + t] = excl;
    __syncthreads();
    if (t == 255) carry = carry + woff + x;
    __syncthreads();
  }
}
__global__ __launch_bounds__(256) void scatter2(const int* __restrict__ c2, const int* __restrict__ u2,
    int* __restrict__ cur_c, int* __restrict__ cur_u, int* __restrict__ adjc_u, uint2* __restrict__ adju2, int NE_)
{
  int e = blockIdx.x * 256 + threadIdx.x;
  if (e >= NE_) return;
  int c = c2[e], u = u2[e];
  int pc = atomicAdd(cur_c + c, 1);
  adjc_u[pc] = u;
  int pu = atomicAdd(cur_u + u, 1);
  uint2 ent; ent.x = (unsigned)c; ent.y = (unsigned)pc;
  adju2[pu] = ent;
}
__global__ __launch_bounds__(256) void scatter3(const int* __restrict__ c3, const int* __restrict__ u3,
    const int* __restrict__ v3, const int* __restrict__ tt, int* __restrict__ cur_c, int* __restrict__ cur_i,
    unsigned* __restrict__ adj3c, uint2* __restrict__ adj3i, int NT_)
{
  int e = blockIdx.x * 256 + threadIdx.x;
  if (e >= NT_) return;
  int c = c3[e], u = u3[e], v = v3[e], tau = tt[e];
  int pc = atomicAdd(cur_c + c, 1);
  adj3c[pc] = (unsigned)u | ((unsigned)v << 15) | ((unsigned)tau << 30);
  int pu = atomicAdd(cur_i + u, 1);
  uint2 eu; eu.x = (unsigned)c | ((unsigned)tau << 15) | ((unsigned)v << 16); eu.y = (unsigned)pc;
  adj3i[pu] = eu;
  int pv = atomicAdd(cur_i + v, 1);
  uint2 ev; ev.x = (unsigned)c | ((unsigned)tau << 15) | ((unsigned)u << 16); ev.y = (unsigned)pc;
  adj3i[pv] = ev;
}

// ---------- order-2 by-c: 16 lanes/edge, online softmax + dQ2 ----------
__global__ __launch_bounds__(256) void e2_rowc(const ushort_t* __restrict__ QK2, const int* __restrict__ cur_c,
    const int* __restrict__ adjc_u, ushort_t* __restrict__ dstage, float* __restrict__ s2c,
    float2* __restrict__ ml2, const float* __restrict__ b2p, const float* __restrict__ l2p)
{
  int wave = threadIdx.x >> 6, lane = threadIdx.x & 63;
  int r = blockIdx.x * 4 + wave;
  int quarter = lane >> 4, sub = lane & 15;
  float b2s = fminf(softplus_f(*b2p), 5.0f) * 0.0625f;
  float lam2 = softplus_f(*l2p);
  int start = (r > 0) ? cur_c[r - 1] : 0;
  int end = cur_c[r];
  const ushort_t* qrow = QK2 + (size_t)r * 512 + sub * 16;
  float qf[16];
  unpack16(*(const uint4*)qrow, *(const uint4*)(qrow + 8), qf);
  float m = -1e30f, l = 0.f;
  float a[16] = {};
  for (int p = start + quarter; p < end; p += 4){
    int u = adjc_u[p];
    const ushort_t* krow = QK2 + (size_t)u * 512 + 256 + sub * 16;
    float kf[16];
    unpack16(*(const uint4*)krow, *(const uint4*)(krow + 8), kf);
    float d = 0.f;
    #pragma unroll
    for (int j = 0; j < 16; ++j) d += qf[j] * kf[j];
    d += __shfl_xor(d, 1); d += __shfl_xor(d, 2); d += __shfl_xor(d, 4); d += __shfl_xor(d, 8);
    float s = d * b2s;
    if (sub == 0) s2c[p] = s;
    float mn = fmaxf(m, s);
    float sc = expf(m - mn);
    float pt = expf(s - mn);
    l = l * sc + pt;
    #pragma unroll
    for (int j = 0; j < 16; ++j) a[j] = a[j] * sc + pt * kf[j];
    m = mn;
  }
  float M = fmaxf(m, __shfl_xor(m, 16)); M = fmaxf(M, __shfl_xor(M, 32));
  float scq = expf(m - M);
  float L = l * scq;
  L += __shfl_xor(L, 16); L += __shfl_xor(L, 32);
  #pragma unroll
  for (int j = 0; j < 16; ++j){
    float x = a[j] * scq;
    x += __shfl_xor(x, 16); x += __shfl_xor(x, 32);
    a[j] = x;
  }
  float linv = 0.f, coef = 0.f;
  if (end > start){ linv = 1.0f / L; coef = -lam2 * 0.0625f * linv; }
  if (lane == 0){
    float2 ml; ml.x = M; ml.y = linv;
    ml2[r] = ml;
  }
  if (quarter == 0){
    ushort_t* dst = dstage + (size_t)r * 512 + sub * 16;
    uint4 p0, p1;
    p0.x = pack2(coef*a[0], coef*a[1]);   p0.y = pack2(coef*a[2], coef*a[3]);
    p0.z = pack2(coef*a[4], coef*a[5]);   p0.w = pack2(coef*a[6], coef*a[7]);
    p1.x = pack2(coef*a[8], coef*a[9]);   p1.y = pack2(coef*a[10], coef*a[11]);
    p1.z = pack2(coef*a[12], coef*a[13]); p1.w = pack2(coef*a[14], coef*a[15]);
    *(uint4*)dst = p0; *(uint4*)(dst + 8) = p1;
  }
}

// ---------- order-2 by-u: stored scores, dK2 ----------
__global__ __launch_bounds__(256) void e2_rowu(const ushort_t* __restrict__ QK2, const int* __restrict__ cur_u,
    const uint2* __restrict__ adju2, const float* __restrict__ s2c, const float2* __restrict__ ml2,
    ushort_t* __restrict__ dstage, const float* __restrict__ l2p)
{
  int wave = threadIdx.x >> 6, lane = threadIdx.x & 63;
  int r = blockIdx.x * 4 + wave;
  int quarter = lane >> 4, sub = lane & 15;
  float lam2 = softplus_f(*l2p);
  int start = (r > 0) ? cur_u[r - 1] : 0;
  int end = cur_u[r];
  float a[16] = {};
  for (int p = start + quarter; p < end; p += 4){
    uint2 ent = adju2[p];
    int c = (int)ent.x;
    float2 ml = ml2[c];
    float pe = expf(s2c[ent.y] - ml.x) * ml.y;
    const ushort_t* qrow = QK2 + (size_t)c * 512 + sub * 16;
    float qf[16];
    unpack16(*(const uint4*)qrow, *(const uint4*)(qrow + 8), qf);
    #pragma unroll
    for (int j = 0; j < 16; ++j) a[j] += pe * qf[j];
  }
  #pragma unroll
  for (int j = 0; j < 16; ++j){
    float x = a[j];
    x += __shfl_xor(x, 16); x += __shfl_xor(x, 32);
    a[j] = x;
  }
  float coef = -lam2 * 0.0625f;
  if (quarter == 0){
    ushort_t* dst = dstage + (size_t)r * 512 + 256 + sub * 16;
    uint4 p0, p1;
    p0.x = pack2(coef*a[0], coef*a[1]);   p0.y = pack2(coef*a[2], coef*a[3]);
    p0.z = pack2(coef*a[4], coef*a[5]);   p0.w = pack2(coef*a[6], coef*a[7]);
    p1.x = pack2(coef*a[8], coef*a[9]);   p1.y = pack2(coef*a[10], coef*a[11]);
    p1.z = pack2(coef*a[12], coef*a[13]); p1.w = pack2(coef*a[14], coef*a[15]);
    *(uint4*)dst = p0; *(uint4*)(dst + 8) = p1;
  }
}

// ---------- order-3 by-c: online softmax + dQ3, wave per row, T in LDS ----------
__global__ __launch_bounds__(256) void e3_rowc(const ushort_t* __restrict__ QK3, const float* __restrict__ Tt,
    const int* __restrict__ cur_c, const unsigned* __restrict__ adj3c, ushort_t* __restrict__ dstage,
    float* __restrict__ s3c, float2* __restrict__ ml3, const float* __restrict__ b3p,
    const float* __restrict__ l3p)
{
  __shared__ float sT[1024];
  int wave = threadIdx.x >> 6, lane = threadIdx.x & 63;
  int r = blockIdx.x * 4 + wave;
  for (int i = threadIdx.x; i < 1024; i += 256) sT[i] = Tt[i];
  __syncthreads();
  float b3s = fminf(softplus_f(*b3p), 5.0f) * 0.0625f;
  float lam3 = softplus_f(*l3p);
  int start = (r > 0) ? cur_c[r - 1] : 0;
  int end = cur_c[r];
  uint4 qw = *(const uint4*)(QK3 + (size_t)r * 1024 + lane * 8);
  float q[8] = {bflo(qw.x),bfhi(qw.x),bflo(qw.y),bfhi(qw.y),bflo(qw.z),bfhi(qw.z),bflo(qw.w),bfhi(qw.w)};
  float T0[8], T1[8];
  #pragma unroll
  for (int j = 0; j < 8; ++j){ T0[j] = sT[lane * 8 + j]; T1[j] = sT[512 + lane * 8 + j]; }
  float m = -1e30f, l = 0.f;
  float a[8] = {};
  for (int p = start; p < end; ++p){
    unsigned ent = adj3c[p];
    int u = ent & 32767, v = (ent >> 15) & 32767, tau = (ent >> 30) & 1;
    uint4 bw = *(const uint4*)(QK3 + (size_t)u * 1024 + 512 + lane * 8);
    uint4 cw = *(const uint4*)(QK3 + (size_t)v * 1024 + 512 + lane * 8);
    float kb[8] = {bflo(bw.x),bfhi(bw.x),bflo(bw.y),bfhi(bw.y),bflo(bw.z),bfhi(bw.z),bflo(bw.w),bfhi(bw.w)};
    float kc[8] = {bflo(cw.x),bfhi(cw.x),bflo(cw.y),bfhi(cw.y),bflo(cw.z),bfhi(cw.z),bflo(cw.w),bfhi(cw.w)};
    float prod[8];
    float d = 0.f;
    #pragma unroll
    for (int j = 0; j < 8; ++j){
      float tj = tau ? T1[j] : T0[j];
      prod[j] = kb[j] * kc[j] * tj;
      d += q[j] * prod[j];
    }
    #pragma unroll
    for (int o = 32; o > 0; o >>= 1) d += __shfl_xor(d, o);
    float s = d * b3s;
    if (lane == 0) s3c[p] = s;
    float mn = fmaxf(m, s);
    float sc = expf(m - mn);
    float pt = expf(s - mn);
    l = l * sc + pt;
    #pragma unroll
    for (int j = 0; j < 8; ++j) a[j] = a[j]*sc + pt*prod[j];
    m = mn;
  }
  float linv = 0.f, coef = 0.f;
  if (end > start){ linv = 1.0f / l; coef = -lam3 * 0.0625f * linv; }
  uint4 o4;
  o4.x = pack2(coef*a[0], coef*a[1]); o4.y = pack2(coef*a[2], coef*a[3]);
  o4.z = pack2(coef*a[4], coef*a[5]); o4.w = pack2(coef*a[6], coef*a[7]);
  *(uint4*)(dstage + (size_t)r * 1024 + lane * 8) = o4;
  if (lane == 0){
    float2 ml; ml.x = m; ml.y = linv;
    ml3[r] = ml;
  }
}

// ---------- order-3 incidence: stored scores, dK3, T in LDS ----------
__global__ __launch_bounds__(256) void e3_rowi(const ushort_t* __restrict__ QK3, const float* __restrict__ Tt,
    const int* __restrict__ cur_i, const uint2* __restrict__ adj3i, const float* __restrict__ s3c,
    const float2* __restrict__ ml3, ushort_t* __restrict__ dstage, const float* __restrict__ l3p)
{
  __shared__ float sT[1024];
  int wave = threadIdx.x >> 6, lane = threadIdx.x & 63;
  int r = blockIdx.x * 4 + wave;
  for (int i = threadIdx.x; i < 1024; i += 256) sT[i] = Tt[i];
  __syncthreads();
  float lam3 = softplus_f(*l3p);
  int start = (r > 0) ? cur_i[r - 1] : 0;
  int end = cur_i[r];
  float T0[8], T1[8];
  #pragma unroll
  for (int j = 0; j < 8; ++j){ T0[j] = sT[lane * 8 + j]; T1[j] = sT[512 + lane * 8 + j]; }
  float a[8] = {};
  for (int p = start; p < end; ++p){
    uint2 ent = adj3i[p];
    int c = ent.x & 32767, tau = (ent.x >> 15) & 1, other = (ent.x >> 16) & 32767;
    float2 ml = ml3[c];
    float pe = expf(s3c[ent.y] - ml.x) * ml.y;
    uint4 qw = *(const uint4*)(QK3 + (size_t)c * 1024 + lane * 8);
    uint4 ow = *(const uint4*)(QK3 + (size_t)other * 1024 + 512 + lane * 8);
    float q[8] = {bflo(qw.x),bfhi(qw.x),bflo(qw.y),bfhi(qw.y),bflo(qw.z),bfhi(qw.z),bflo(qw.w),bfhi(qw.w)};
    float ko[8] = {bflo(ow.x),bfhi(ow.x),bflo(ow.y),bfhi(ow.y),bflo(ow.z),bfhi(ow.z),bflo(ow.w),bfhi(ow.w)};
    #pragma unroll
    for (int j = 0; j < 8; ++j){
      float tj = tau ? T1[j] : T0[j];
      a[j] += pe * q[j] * ko[j] * tj;
    }
  }
  float coef = -lam3 * 0.0625f;
  uint4 o4;
  o4.x = pack2(coef*a[0], coef*a[1]); o4.y = pack2(coef*a[2], coef*a[3]);
  o4.z = pack2(coef*a[4], coef*a[5]); o4.w = pack2(coef*a[6], coef*a[7]);
  *(uint4*)(dstage + (size_t)r * 1024 + 512 + lane * 8) = o4;
}

// ---------- reduce: sum of plain floats ----------
__global__ __launch_bounds__(256) void reduce_sum(const float* __restrict__ v, int n, float* __restrict__ accum)
{
  __shared__ float sbuf[8];
  float acc = 0.f;
  for (int i = blockIdx.x * 256 + threadIdx.x; i < n; i += gridDim.x * 256) acc += v[i];
  float bs = block_reduce_sum(acc, sbuf);
  if (threadIdx.x == 0) atomicAdd(accum, bs);
}
// ---------- reduce: sum of lse from (m, linv) pairs ----------
__global__ __launch_bounds__(256) void reduce_ml(const float2* __restrict__ ml, int n, float* __restrict__ accum)
{
  __shared__ float sbuf[8];
  float acc = 0.f;
  for (int i = blockIdx.x * 256 + threadIdx.x; i < n; i += gridDim.x * 256){
    float2 v = ml[i];
    if (v.y > 0.f) acc += v.x - logf(v.y);
  }
  float bs = block_reduce_sum(acc, sbuf);
  if (threadIdx.x == 0) atomicAdd(accum, bs);
}

// ---------- LN backward + clips + update ----------
__global__ __launch_bounds__(256) void ln_bwd_update(const float* __restrict__ X, const float* __restrict__ dG,
    const float* __restrict__ gamma, const float* __restrict__ mean, const float* __restrict__ rstd,
    const float* __restrict__ step_p, float* __restrict__ out)
{
  __shared__ float sbuf[8];
  int n = blockIdx.x, t = threadIdx.x;
  size_t idx = (size_t)n * D_ + t;
  float x = X[idx];
  float rs = rstd[n];
  float xh = (x - mean[n]) * rs;
  float dxh = dG[idx] * gamma[t];
  float s1 = block_reduce_sum(dxh, sbuf) * (1.0f / D_);
  float s2v = block_reduce_sum(dxh * xh, sbuf) * (1.0f / D_);
  float dx = rs * (dxh - s1 - xh * s2v);
  float gn2 = block_reduce_sum(dx * dx, sbuf);
  float gn = fmaxf(sqrtf(gn2), 1e-6f);
  float gsc = fminf(1.0f / gn, 1.0f);
  float stp = step_p[0] * 0.9999f;
  float xn = x - stp * gsc * dx;
  float sn2 = block_reduce_sum(xn * xn, sbuf);
  float sn = fmaxf(sqrtf(sn2), 1e-6f);
  float ssc = fminf(10.0f / sn, 1.0f);
  out[idx] = xn * ssc;
}

// ---------- final energy scalar ----------
__global__ void efinal(const float* __restrict__ accum, const float* l2p, const float* l3p, const float* lmp,
    const float* b2p, const float* b3p, const float* bmp, float* __restrict__ outE)
{
  float l2 = softplus_f(*l2p), l3 = softplus_f(*l3p), lm = softplus_f(*lmp);
  float b2 = fminf(softplus_f(*b2p), 5.0f);
  float b3 = fminf(softplus_f(*b3p), 5.0f);
  float bm = fminf(softplus_f(*bmp), 5.0f);
  *outE = -(l2 / b2) * accum[0] - (l3 / b3) * accum[1] - (lm / bm) * accum[2];
}

static inline void zfill(void* p, size_t nElems, hipStream_t stream){
  size_t n4 = nElems / 4;
  int blocks = (int)(((n4 + 255) / 256) < 16384 ? ((n4 + 255) / 256) : 16384);
  if (blocks < 1) blocks = 1;
  zerok<<<blocks, 256, 0, stream>>>((float4*)p, n4);
}

extern "C" void kernel_launch(void* const* d_in, const int* in_sizes, int n_in,
                              void* d_out, int out_size, void* d_ws, size_t ws_size,
                              hipStream_t stream)
{
  const float* X     = (const float*)d_in[0];
  const int*   c2    = (const int*)d_in[1];
  const int*   u2    = (const int*)d_in[2];
  const int*   c3    = (const int*)d_in[3];
  const int*   u3    = (const int*)d_in[4];
  const int*   v3    = (const int*)d_in[5];
  const int*   tt    = (const int*)d_in[6];
  const float* stepp = (const float*)d_in[7];
  const float* gamma = (const float*)d_in[8];
  const float* beta  = (const float*)d_in[9];
  const float* W_Q2  = (const float*)d_in[10];
  const float* W_K2  = (const float*)d_in[11];
  const float* W_Q3  = (const float*)d_in[12];
  const float* W_K3  = (const float*)d_in[13];
  const float* T_tau = (const float*)d_in[14];
  const float* W_Qm  = (const float*)d_in[15];
  const float* W_Km  = (const float*)d_in[16];
  const float* B_mem = (const float*)d_in[17];
  const float* l2p   = (const float*)d_in[18];
  const float* l3p   = (const float*)d_in[19];
  const float* lmp   = (const float*)d_in[20];
  const float* b2p   = (const float*)d_in[21];
  const float* b3p   = (const float*)d_in[22];
  const float* bmp   = (const float*)d_in[23];

  const int N  = in_sizes[0] / D_;
  const int NE = in_sizes[1];
  const int NT = in_sizes[3];
  const size_t ND = (size_t)N * D_;

  // ---- byte arena ----
  char* base = (char*)d_ws;
  size_t off = 0;
  auto alloc = [&](size_t bytes) -> void* {
    void* p = base + off;
    off += (bytes + 255) & ~(size_t)255;
    return p;
  };
  ushort_t* Gb    = (ushort_t*)alloc(ND * 2);            // 16 MB
  ushort_t* bufA  = (ushort_t*)alloc(ND * 4 * 2);        // 64 MB: fwd QK per phase
  ushort_t* bufB  = (ushort_t*)alloc(ND * 4 * 2);        // 64 MB: grad staging / Sm+P'
  int*      curs  = (int*)     alloc((size_t)N * 4 * 4);
  int*      adjc_u= (int*)     alloc((size_t)NE * 4);
  uint2*    adju2 = (uint2*)   alloc((size_t)NE * 8);
  unsigned* adj3c = (unsigned*)alloc((size_t)NT * 4);
  uint2*    adj3i = (uint2*)   alloc((size_t)NT * 2 * 8);
  float*    s2c   = (float*)   alloc((size_t)NE * 4);
  float*    s3c   = (float*)   alloc((size_t)NT * 4);
  float2*   ml2   = (float2*)  alloc((size_t)N * 8);
  float2*   ml3   = (float2*)  alloc((size_t)N * 8);
  ushort_t* Kmb   = (ushort_t*)alloc((size_t)128 * 256 * 2);   // padded [128,256] bf16
  ushort_t* KWb   = (ushort_t*)alloc((size_t)256 * 128 * 2);   // KW [256,128] bf16
  float*    meanb = (float*)   alloc((size_t)N * 4);
  float*    rstdb = (float*)   alloc((size_t)N * 4);
  float*    lseM  = (float*)   alloc((size_t)N * 4);
  float*    accum = (float*)   alloc(64);
  ushort_t* WtQm  = (ushort_t*)alloc(65536 * 2);
  ushort_t* WtF2  = (ushort_t*)alloc(131072 * 2);
  ushort_t* WtF3  = (ushort_t*)alloc(262144 * 2);
  ushort_t* WbQm  = (ushort_t*)alloc(65536 * 2);
  ushort_t* Bt2   = (ushort_t*)alloc(131072 * 2);
  ushort_t* Bt3   = (ushort_t*)alloc(262144 * 2);

  int* curc2 = curs;
  int* curu2 = curs + N;
  int* curc3 = curs + 2 * N;
  int* curi3 = curs + 3 * N;
  float* out = (float*)d_out;
  // mem-phase views of bufB: Sm fp32 [N,128], then P' bf16 [N,128]
  float*    Sm = (float*)bufB;
  ushort_t* Pb = (ushort_t*)(Sm + (size_t)N * 128);

  zfill(curs, (size_t)N * 4, stream);
  zfill(accum, 16, stream);
  zfill(Kmb, 128 * 256 / 2, stream);   // 128*256 ushorts = 16384 float4-equiv... (elems/4 handled in zfill)

  // 1. LN forward + weight prep
  ln_fwd<<<N, 256, 0, stream>>>(X, gamma, beta, Gb, meanb, rstdb);
  wprep_all<<<(917504 + 255) / 256, 256, 0, stream>>>(W_Q2, W_K2, W_Q3, W_K3, W_Qm,
      WtQm, WtF2, WtF3, WbQm, Bt2, Bt3);

  // CSR build
  hist2<<<(NE + 255) / 256, 256, 0, stream>>>(c2, u2, curc2, curu2, NE);
  hist3<<<(NT + 255) / 256, 256, 0, stream>>>(c3, u3, v3, curc3, curi3, NT);
  scan_excl4<<<4, 256, 0, stream>>>(curs, N);
  scatter2<<<(NE + 255) / 256, 256, 0, stream>>>(c2, u2, curc2, curu2, adjc_u, adju2, NE);
  scatter3<<<(NT + 255) / 256, 256, 0, stream>>>(c3, u3, v3, tt, curc3, curi3, adj3c, adj3i, NT);

  dim3 g256(2, N / 128), g512(4, N / 128), g1024(8, N / 128);

  // 2. memory phase (all GEMM-shaped)
  km_kernel<<<KSLOT, 256, 0, stream>>>(B_mem, W_Km, Kmb);                       // Km bf16 (padded)
  gemm_bt_mfma<2><<<dim3(1, 2), 256, 0, stream>>>(WbQm, Kmb, KWb, 256, 128);    // KW = W_Qm Km^T
  gemm_bt_mfma<2><<<g256, 256, 0, stream>>>(Gb, WtQm, bufA, D_, D_);            // Qm (bf16)
  gemm_bt_mfma<0><<<dim3(1, N / 128), 256, 0, stream>>>(bufA, Kmb, Sm, 256, 128); // Sm = Qm Km^T
  softmax32<<<N / 8, 256, 0, stream>>>(Sm, Pb, lseM, bmp, lmp);                 // P' (coef folded) + lse
  gemm_bt_mfma<0><<<g256, 256, 0, stream>>>(Pb, KWb, out, 128, D_);             // dG = P' KW^T
  reduce_sum<<<64, 256, 0, stream>>>(lseM, N, accum + 2);

  // 3. order-2 phase
  gemm_bt_mfma<2><<<g512, 256, 0, stream>>>(Gb, WtF2, bufA, D_, 512);           // [Q2|K2]
  e2_rowc<<<N / 4, 256, 0, stream>>>(bufA, curc2, adjc_u, bufB, s2c, ml2, b2p, l2p);
  e2_rowu<<<N / 4, 256, 0, stream>>>(bufA, curu2, adju2, s2c, ml2, bufB, l2p);
  gemm_bt_mfma<1><<<g256, 256, 0, stream>>>(bufB, Bt2, out, 512, D_);           // dG += [dQ2|dK2] Bt2^T
  reduce_ml<<<64, 256, 0, stream>>>(ml2, N, accum + 0);

  // 4. order-3 phase
  gemm_bt_mfma<2><<<g1024, 256, 0, stream>>>(Gb, WtF3, bufA, D_, 1024);         // [Q3|K3]
  e3_rowc<<<N / 4, 256, 0, stream>>>(bufA, T_tau, curc3, adj3c, bufB, s3c, ml3, b3p, l3p);
  e3_rowi<<<N / 4, 256, 0, stream>>>(bufA, T_tau, curi3, adj3i, s3c, ml3, bufB, l3p);
  gemm_bt_mfma<1><<<g256, 256, 0, stream>>>(bufB, Bt3, out, 1024, D_);          // dG += [dQ3|dK3] Bt3^T
  reduce_ml<<<64, 256, 0, stream>>>(ml3, N, accum + 1);

  // 5. LN backward + clips + update
  ln_bwd_update<<<N, 256, 0, stream>>>(X, out, gamma, meanb, rstdb, stepp, out);

  // 6. energy scalar
  efinal<<<1, 1, 0, stream>>>(accum, l2p, l3p, lmp, b2p, b3p, bmp, out + ND);
}